// Round 5
// baseline (459.156 us; speedup 1.0000x reference)
//
#include <hip/hip_runtime.h>

typedef _Float16 half8 __attribute__((ext_vector_type(8)));
typedef _Float16 half4 __attribute__((ext_vector_type(4)));
typedef float f32x4 __attribute__((ext_vector_type(4)));
typedef float f32x16 __attribute__((ext_vector_type(16)));

// ---------------- prologue: cast + retile weights to fp16 MFMA tiles --------
// Tile (nb, ks): n in [nb*32,+32), k in [ks*16,+16), 512 halfs; lane l of a
// wave reads its A-fragment at tile_base + l*8 halfs (= l*16 bytes) -> one
// coalesced 1KB load. offset within tile for (lr=n&31, kk=k&15):
//   lr*8 + (kk>>3)*256 + (kk&7)   [halfs]
__global__ void prep_weights(const float* __restrict__ W1, const float* __restrict__ W2,
                             const float* __restrict__ W3, const float* __restrict__ W4,
                             _Float16* __restrict__ wt1, _Float16* __restrict__ wt2,
                             _Float16* __restrict__ wt3, _Float16* __restrict__ w4h) {
  int idx = blockIdx.x * blockDim.x + threadIdx.x;
  if (idx < 512 * 256) {  // W1: K=256, N=512, KS=16
    int k = idx >> 9, n = idx & 511;
    int off = (((n >> 5) * 16 + (k >> 4)) << 9) + (n & 31) * 8 + (((k >> 3) & 1) << 8) + (k & 7);
    wt1[off] = (_Float16)W1[idx];
    return;
  }
  int i2 = idx - 512 * 256;
  if (i2 < 512 * 512) {  // W2: K=512, N=512, KS=32
    int k = i2 >> 9, n = i2 & 511;
    int off = (((n >> 5) * 32 + (k >> 4)) << 9) + (n & 31) * 8 + (((k >> 3) & 1) << 8) + (k & 7);
    wt2[off] = (_Float16)W2[i2];
    return;
  }
  int i3 = i2 - 512 * 512;
  if (i3 < 512 * 256) {  // W3: K=512, N=256, KS=32
    int k = i3 >> 8, n = i3 & 255;
    int off = (((n >> 5) * 32 + (k >> 4)) << 9) + (n & 31) * 8 + (((k >> 3) & 1) << 8) + (k & 7);
    wt3[off] = (_Float16)W3[i3];
    return;
  }
  int i4 = i3 - 512 * 256;
  if (i4 < 256) w4h[i4] = (_Float16)W4[i4];
}

// silu with raw v_rcp_f32 (no IEEE div sequence); ~1ulp, well within tolerance
__device__ __forceinline__ float fast_silu(float s) {
  float e = __expf(-s);
  float d = 1.0f + e;
  float r;
  asm("v_rcp_f32 %0, %1" : "=v"(r) : "v"(d));
  return s * r;
}

// ---------------- fused MLP ----------------
// R13 geometry: ONE 1024-thread block = 16 waves = 128 atoms per CU.
// Wave wid: wfeat = wid&7 (feature-group), ahalf = wid>>3 (atom 64-half).
// Per-wave shape is IDENTICAL to the verified R8/R10 baseline (FT=2, AT=2,
// acc=64 AGPR, <=128 unified regs -> 16 waves/CU), so numerics and register
// budget are unchanged. What changes: wave pairs (wid, wid+8) share wfeat
// and read IDENTICAL weight addresses within a few hundred cycles
// (barrier-synced) -> second reader hits L1 -> A-stream from L2 HALVES.
// Staging + L4 run once per 128 atoms instead of twice.
// Evidence trail: R9 prefetch thrashed L3 (FAILED). R10 bias-fold+pre-
// barrier silu (NEUTRAL, kept). R11 falsified inter-block skew. R12
// (AT=4, 8 waves/CU) falsified the naive weight-BW theory but showed
// per-wave amortization works and 16 waves/CU are needed for latency
// cover. True MFMA issue occupancy is ~8% (MfmaUtil's gfx94x formula
// assumes ~32cyc MFMAs); the binding resource is operand streaming:
// ~2MB A + 2MB B per 128-atom generation per CU.

#define MFMA(a, b, c) __builtin_amdgcn_mfma_f32_32x32x16_f16(a, b, c, 0, 0, 0)

template <int FT, int AT, int KS, int PIN, int POUT>
__device__ __forceinline__ void layer(const _Float16* __restrict__ wt,
                                      const float* __restrict__ bias,
                                      char* __restrict__ Hb,
                                      int wfeat, int arow0, int lane) {
  const int lr = lane & 31;
  const int lh = lane >> 5;
  const int n0 = wfeat * (FT * 32);
  const int s0 = (lr & 31) << 4;  // row swizzle; (arow0+a*32+lr)&31 == lr&31
  const char* Bp = Hb + (size_t)(arow0 + lr) * PIN;
  const char* wp = (const char*)wt + (size_t)(wfeat * FT * KS) * 1024 + lh * 512 + lr * 16;

  // init acc = bias (folds epilogue bias-add into MFMA C-in; bv transient)
  f32x16 acc[FT][AT];
#pragma unroll
  for (int f = 0; f < FT; ++f)
#pragma unroll
    for (int rg = 0; rg < 4; ++rg) {
      const int feat = n0 + f * 32 + rg * 8 + lh * 4;
      const f32x4 bv = *(const f32x4*)(bias + feat);
#pragma unroll
      for (int a = 0; a < AT; ++a)
#pragma unroll
        for (int r = 0; r < 4; ++r) acc[f][a][rg * 4 + r] = bv[r];
    }

  half8 Af[FT], Ag[FT], Bf[AT], Bg[AT];
#pragma unroll
  for (int f = 0; f < FT; ++f) Af[f] = *(const half8*)(wp + f * (KS * 1024));
#pragma unroll
  for (int a = 0; a < AT; ++a)
    Bf[a] = *(const half8*)(Bp + a * 32 * PIN + ((lh * 16) ^ s0));

#pragma unroll 1
  for (int ks = 0; ks < KS - 2; ks += 2) {
    // prefetch ks+1 into g-buffers
#pragma unroll
    for (int f = 0; f < FT; ++f)
      Ag[f] = *(const half8*)(wp + f * (KS * 1024) + (ks + 1) * 1024);
#pragma unroll
    for (int a = 0; a < AT; ++a)
      Bg[a] = *(const half8*)(Bp + a * 32 * PIN + (((ks + 1) * 32 + lh * 16) ^ s0));
    // compute ks
#pragma unroll
    for (int f = 0; f < FT; ++f)
#pragma unroll
      for (int a = 0; a < AT; ++a) acc[f][a] = MFMA(Af[f], Bf[a], acc[f][a]);
    // prefetch ks+2 into f-buffers
#pragma unroll
    for (int f = 0; f < FT; ++f)
      Af[f] = *(const half8*)(wp + f * (KS * 1024) + (ks + 2) * 1024);
#pragma unroll
    for (int a = 0; a < AT; ++a)
      Bf[a] = *(const half8*)(Bp + a * 32 * PIN + (((ks + 2) * 32 + lh * 16) ^ s0));
    // compute ks+1
#pragma unroll
    for (int f = 0; f < FT; ++f)
#pragma unroll
      for (int a = 0; a < AT; ++a) acc[f][a] = MFMA(Ag[f], Bg[a], acc[f][a]);
  }
  // tail: ks = KS-2 in f-buffers; prefetch KS-1; compute both
#pragma unroll
  for (int f = 0; f < FT; ++f)
    Ag[f] = *(const half8*)(wp + f * (KS * 1024) + (KS - 1) * 1024);
#pragma unroll
  for (int a = 0; a < AT; ++a)
    Bg[a] = *(const half8*)(Bp + a * 32 * PIN + ((((KS - 1) * 32) + lh * 16) ^ s0));
#pragma unroll
  for (int f = 0; f < FT; ++f)
#pragma unroll
    for (int a = 0; a < AT; ++a) acc[f][a] = MFMA(Af[f], Bf[a], acc[f][a]);
#pragma unroll
  for (int f = 0; f < FT; ++f)
#pragma unroll
    for (int a = 0; a < AT; ++a) acc[f][a] = MFMA(Ag[f], Bg[a], acc[f][a]);

  // silu in-place on private accumulators — BEFORE the barrier (R10).
#pragma unroll
  for (int f = 0; f < FT; ++f)
#pragma unroll
    for (int a = 0; a < AT; ++a)
#pragma unroll
      for (int j = 0; j < 16; ++j) acc[f][a][j] = fast_silu(acc[f][a][j]);

  __syncthreads();  // all waves finished reading input region; safe to overwrite

  // post-barrier: cvt -> fp16, write swizzled (2-way, free)
#pragma unroll
  for (int f = 0; f < FT; ++f) {
#pragma unroll
    for (int rg = 0; rg < 4; ++rg) {
      const int feat = n0 + f * 32 + rg * 8 + lh * 4;
#pragma unroll
      for (int a = 0; a < AT; ++a) {
        half4 h;
#pragma unroll
        for (int r = 0; r < 4; ++r) h[r] = (_Float16)acc[f][a][rg * 4 + r];
        const int row = arow0 + a * 32 + lr;
        *(half4*)(Hb + (size_t)row * POUT + ((feat * 2) ^ ((row & 31) << 4))) = h;
      }
    }
  }
}

extern "C" __global__ void __launch_bounds__(1024, 4)
mlp_kernel(const float* __restrict__ X, const int* __restrict__ species,
           const _Float16* __restrict__ wt1, const float* __restrict__ b1,
           const _Float16* __restrict__ wt2, const float* __restrict__ b2,
           const _Float16* __restrict__ wt3, const float* __restrict__ b3,
           const _Float16* __restrict__ w4h, const float* __restrict__ b4,
           float* __restrict__ out, int natoms) {
  __shared__ __align__(16) char H[128 * 1024];
  const int tid = threadIdx.x;
  const int lane = tid & 63;
  const int wid = tid >> 6;       // 16 waves
  const int wfeat = wid & 7;      // 8 feature-groups
  const int arow0 = (wid >> 3) * 64;  // 2 atom-halves
  const long abase = (long)blockIdx.x * 128;

  // ---- stage X[128x256] -> fp16 LDS, pitch 512B, swizzled ----
  {
    const int r = tid >> 3, cg = tid & 7;  // 8 threads per row, 128 rows
    long g = abase + r;
    const long gmax = (long)natoms - 1;
    if (g > gmax) g = gmax;  // clamp: pad rows read a valid row, never stored
    const float* xp = X + g * 256;
    const int sw = (r & 31) << 4;
#pragma unroll
    for (int j = 0; j < 8; ++j) {
      const int colh = cg * 4 + j * 32;
      f32x4 v = *(const f32x4*)(xp + colh);
      half4 h;
#pragma unroll
      for (int e = 0; e < 4; ++e) h[e] = (_Float16)v[e];
      *(half4*)(H + r * 512 + ((colh * 2) ^ sw)) = h;
    }
  }
  __syncthreads();

  // L1: Xh[128x256] -> H1[128x512]   (8 wfeat x FT=2 -> 512 feats)
  layer<2, 2, 16, 512, 1024>(wt1, b1, H, wfeat, arow0, lane);
  __syncthreads();
  // L2: H1 -> H2[128x512]
  layer<2, 2, 32, 1024, 1024>(wt2, b2, H, wfeat, arow0, lane);
  __syncthreads();
  // L3: H2 -> H3[128x256]            (8 wfeat x FT=1 -> 256 feats)
  layer<1, 2, 32, 1024, 1024>(wt3, b3, H, wfeat, arow0, lane);
  __syncthreads();

  // L4: out[atom] = dot(H3[atom], w4) + b4, masked by species
  const int atom = tid >> 3, part = tid & 7;  // 8 threads per atom, 128 atoms
  const int sw = (atom & 31) << 4;
  const char* h3 = H + (size_t)atom * 1024;
  const _Float16* w4p = w4h + part * 32;
  float sum = 0.0f;
#pragma unroll
  for (int j = 0; j < 4; ++j) {
    half8 h = *(const half8*)(h3 + ((part * 64 + j * 16) ^ sw));
    half8 w = *(const half8*)(w4p + j * 8);
#pragma unroll
    for (int e = 0; e < 8; ++e) sum += (float)h[e] * (float)w[e];
  }
  sum += __shfl_xor(sum, 1);
  sum += __shfl_xor(sum, 2);
  sum += __shfl_xor(sum, 4);
  if (part == 0) {
    const long g = abase + atom;
    if (g < natoms) {
      float r = sum + b4[0];
      out[g] = (species[g] >= 0) ? r : 0.0f;
    }
  }
}

extern "C" void kernel_launch(void* const* d_in, const int* in_sizes, int n_in,
                              void* d_out, int out_size, void* d_ws, size_t ws_size,
                              hipStream_t stream) {
  const float* X = (const float*)d_in[0];
  const int* species = (const int*)d_in[1];
  const float* W1 = (const float*)d_in[2];
  const float* b1 = (const float*)d_in[3];
  const float* W2 = (const float*)d_in[4];
  const float* b2 = (const float*)d_in[5];
  const float* W3 = (const float*)d_in[6];
  const float* b3 = (const float*)d_in[7];
  const float* W4 = (const float*)d_in[8];
  const float* b4 = (const float*)d_in[9];
  float* out = (float*)d_out;
  const int natoms = in_sizes[0] / 256;

  char* ws = (char*)d_ws;
  _Float16* wt1 = (_Float16*)(ws);                             // 512*256*2 B
  _Float16* wt2 = (_Float16*)(ws + 262144);                    // 512*512*2 B
  _Float16* wt3 = (_Float16*)(ws + 262144 + 524288);           // 256*512*2 B
  _Float16* w4h = (_Float16*)(ws + 262144 + 524288 + 262144);  // 512 B

  const int prep_total = 512 * 256 + 512 * 512 + 256 * 512 + 256;
  hipLaunchKernelGGL(prep_weights, dim3((prep_total + 255) / 256), dim3(256), 0, stream,
                     W1, W2, W3, W4, wt1, wt2, wt3, w4h);

  const int nblocks = (natoms + 127) / 128;
  hipLaunchKernelGGL(mlp_kernel, dim3(nblocks), dim3(1024), 0, stream,
                     X, species, wt1, b1, wt2, b2, wt3, b3, w4h, b4, out, natoms);
}

// Round 7
// 404.660 us; speedup vs baseline: 1.1347x; 1.1347x over previous
//
#include <hip/hip_runtime.h>

typedef _Float16 half8 __attribute__((ext_vector_type(8)));
typedef _Float16 half4 __attribute__((ext_vector_type(4)));
typedef float f32x4 __attribute__((ext_vector_type(4)));
typedef float f32x16 __attribute__((ext_vector_type(16)));

// ---------------- prologue: cast + retile weights to fp16 MFMA tiles --------
// Tile (nb, ks): n in [nb*32,+32), k in [ks*16,+16), 512 halfs; lane l of a
// wave reads its A-fragment at tile_base + l*8 halfs (= l*16 bytes) -> one
// coalesced 1KB load. offset within tile for (lr=n&31, kk=k&15):
//   lr*8 + (kk>>3)*256 + (kk&7)   [halfs]
__global__ void prep_weights(const float* __restrict__ W1, const float* __restrict__ W2,
                             const float* __restrict__ W3, const float* __restrict__ W4,
                             _Float16* __restrict__ wt1, _Float16* __restrict__ wt2,
                             _Float16* __restrict__ wt3, _Float16* __restrict__ w4h) {
  int idx = blockIdx.x * blockDim.x + threadIdx.x;
  if (idx < 512 * 256) {  // W1: K=256, N=512, KS=16
    int k = idx >> 9, n = idx & 511;
    int off = (((n >> 5) * 16 + (k >> 4)) << 9) + (n & 31) * 8 + (((k >> 3) & 1) << 8) + (k & 7);
    wt1[off] = (_Float16)W1[idx];
    return;
  }
  int i2 = idx - 512 * 256;
  if (i2 < 512 * 512) {  // W2: K=512, N=512, KS=32
    int k = i2 >> 9, n = i2 & 511;
    int off = (((n >> 5) * 32 + (k >> 4)) << 9) + (n & 31) * 8 + (((k >> 3) & 1) << 8) + (k & 7);
    wt2[off] = (_Float16)W2[i2];
    return;
  }
  int i3 = i2 - 512 * 512;
  if (i3 < 512 * 256) {  // W3: K=512, N=256, KS=32
    int k = i3 >> 8, n = i3 & 255;
    int off = (((n >> 5) * 32 + (k >> 4)) << 9) + (n & 31) * 8 + (((k >> 3) & 1) << 8) + (k & 7);
    wt3[off] = (_Float16)W3[i3];
    return;
  }
  int i4 = i3 - 512 * 256;
  if (i4 < 256) w4h[i4] = (_Float16)W4[i4];
}

// ---------------- compaction: append valid atom indices (unordered) --------
// ~9.1% of atoms have species == -1 -> skip them entirely. Order is
// irrelevant (each valid atom writes its own out slot). Masked atoms get
// out[i] = 0 HERE (their threads are otherwise idle), so no memset of out
// and no dependence on out_size units. Per-wave aggregated atomic (G12).
extern "C" __global__ void compact_kernel(const int* __restrict__ species,
                                          int* __restrict__ idx,
                                          int* __restrict__ count,
                                          float* __restrict__ out, int natoms) {
  int i = blockIdx.x * blockDim.x + threadIdx.x;
  if (i >= natoms) return;
  bool valid = species[i] >= 0;
  unsigned long long m = __ballot(valid);
  int lane = threadIdx.x & 63;
  int base = 0;
  if (lane == 0 && m) base = atomicAdd(count, (int)__popcll(m));
  base = __shfl(base, 0);
  if (valid) {
    int off = (int)__popcll(m & ((1ull << lane) - 1));
    idx[base + off] = i;
  } else {
    out[i] = 0.0f;  // masked atoms must be exactly 0
  }
}

// silu with raw v_rcp_f32 (no IEEE div sequence); ~1ulp, well within tolerance
__device__ __forceinline__ float fast_silu(float s) {
  float e = __expf(-s);
  float d = 1.0f + e;
  float r;
  asm("v_rcp_f32 %0, %1" : "=v"(r) : "v"(d));
  return s * r;
}

// ---------------- fused MLP ----------------
// R8 geometry (the verified local optimum): 64 atoms/block, 512 threads =
// 8 waves, FT=2, AT=2, acc = 64 AGPR + 64 arch VGPR = exactly the 128-reg
// budget at 4 waves/EU; LDS 64KB -> 2 blocks/CU -> 16 waves/CU, TWO
// independent barrier domains per CU (R13 proved merging them costs 16%:
// natural inter-block drift covers stalls).
// Evidence trail: R9 FAILED (L3 prefetch thrash). R10 NEUTRAL (bias-fold
// + pre-barrier silu; kept). R11 falsified forced skew. R12 falsified
// occupancy-halving. R13 falsified single-domain L1-pairing. R14 FAILED:
// correctness bug — in_sizes[0] is ELEMENTS, not bytes (natoms was /1024
// -> only 1/4 of atoms computed). Compaction logic itself untested.
// R15 (this round): R14 with natoms divisor fixed and masked-out zeroing
// moved into compact_kernel (no out_size-unit dependence).

#define MFMA(a, b, c) __builtin_amdgcn_mfma_f32_32x32x16_f16(a, b, c, 0, 0, 0)

template <int FT, int AT, int KS, int PIN, int POUT>
__device__ __forceinline__ void layer(const _Float16* __restrict__ wt,
                                      const float* __restrict__ bias,
                                      char* __restrict__ Hb,
                                      int wfeat, int lane) {
  const int lr = lane & 31;
  const int lh = lane >> 5;
  const int n0 = wfeat * (FT * 32);
  const int s0 = (lr & 31) << 4;  // row swizzle; (a*32+lr)&31 == lr&31
  const char* Bp = Hb + lr * PIN;
  const char* wp = (const char*)wt + (size_t)(wfeat * FT * KS) * 1024 + lh * 512 + lr * 16;

  // init acc = bias (folds epilogue bias-add into MFMA C-in; bv transient)
  f32x16 acc[FT][AT];
#pragma unroll
  for (int f = 0; f < FT; ++f)
#pragma unroll
    for (int rg = 0; rg < 4; ++rg) {
      const int feat = n0 + f * 32 + rg * 8 + lh * 4;
      const f32x4 bv = *(const f32x4*)(bias + feat);
#pragma unroll
      for (int a = 0; a < AT; ++a)
#pragma unroll
        for (int r = 0; r < 4; ++r) acc[f][a][rg * 4 + r] = bv[r];
    }

  half8 Af[FT], Ag[FT], Bf[AT], Bg[AT];
#pragma unroll
  for (int f = 0; f < FT; ++f) Af[f] = *(const half8*)(wp + f * (KS * 1024));
#pragma unroll
  for (int a = 0; a < AT; ++a)
    Bf[a] = *(const half8*)(Bp + a * 32 * PIN + ((lh * 16) ^ s0));

#pragma unroll 1
  for (int ks = 0; ks < KS - 2; ks += 2) {
    // prefetch ks+1 into g-buffers
#pragma unroll
    for (int f = 0; f < FT; ++f)
      Ag[f] = *(const half8*)(wp + f * (KS * 1024) + (ks + 1) * 1024);
#pragma unroll
    for (int a = 0; a < AT; ++a)
      Bg[a] = *(const half8*)(Bp + a * 32 * PIN + (((ks + 1) * 32 + lh * 16) ^ s0));
    // compute ks
#pragma unroll
    for (int f = 0; f < FT; ++f)
#pragma unroll
      for (int a = 0; a < AT; ++a) acc[f][a] = MFMA(Af[f], Bf[a], acc[f][a]);
    // prefetch ks+2 into f-buffers
#pragma unroll
    for (int f = 0; f < FT; ++f)
      Af[f] = *(const half8*)(wp + f * (KS * 1024) + (ks + 2) * 1024);
#pragma unroll
    for (int a = 0; a < AT; ++a)
      Bf[a] = *(const half8*)(Bp + a * 32 * PIN + (((ks + 2) * 32 + lh * 16) ^ s0));
    // compute ks+1
#pragma unroll
    for (int f = 0; f < FT; ++f)
#pragma unroll
      for (int a = 0; a < AT; ++a) acc[f][a] = MFMA(Ag[f], Bg[a], acc[f][a]);
  }
  // tail: ks = KS-2 in f-buffers; prefetch KS-1; compute both
#pragma unroll
  for (int f = 0; f < FT; ++f)
    Ag[f] = *(const half8*)(wp + f * (KS * 1024) + (KS - 1) * 1024);
#pragma unroll
  for (int a = 0; a < AT; ++a)
    Bg[a] = *(const half8*)(Bp + a * 32 * PIN + ((((KS - 1) * 32) + lh * 16) ^ s0));
#pragma unroll
  for (int f = 0; f < FT; ++f)
#pragma unroll
    for (int a = 0; a < AT; ++a) acc[f][a] = MFMA(Af[f], Bf[a], acc[f][a]);
#pragma unroll
  for (int f = 0; f < FT; ++f)
#pragma unroll
    for (int a = 0; a < AT; ++a) acc[f][a] = MFMA(Ag[f], Bg[a], acc[f][a]);

  // silu in-place on private accumulators — BEFORE the barrier (R10).
#pragma unroll
  for (int f = 0; f < FT; ++f)
#pragma unroll
    for (int a = 0; a < AT; ++a)
#pragma unroll
      for (int j = 0; j < 16; ++j) acc[f][a][j] = fast_silu(acc[f][a][j]);

  __syncthreads();  // all waves finished reading input region; safe to overwrite

  // post-barrier: cvt -> fp16, write swizzled (2-way, free)
#pragma unroll
  for (int f = 0; f < FT; ++f) {
#pragma unroll
    for (int rg = 0; rg < 4; ++rg) {
      const int feat = n0 + f * 32 + rg * 8 + lh * 4;
#pragma unroll
      for (int a = 0; a < AT; ++a) {
        half4 h;
#pragma unroll
        for (int r = 0; r < 4; ++r) h[r] = (_Float16)acc[f][a][rg * 4 + r];
        const int row = a * 32 + lr;
        *(half4*)(Hb + row * POUT + ((feat * 2) ^ ((row & 31) << 4))) = h;
      }
    }
  }
}

extern "C" __global__ void __launch_bounds__(512, 4)
mlp_kernel(const float* __restrict__ X, const int* __restrict__ species,
           const _Float16* __restrict__ wt1, const float* __restrict__ b1,
           const _Float16* __restrict__ wt2, const float* __restrict__ b2,
           const _Float16* __restrict__ wt3, const float* __restrict__ b3,
           const _Float16* __restrict__ w4h, const float* __restrict__ b4,
           float* __restrict__ out, int natoms,
           const int* __restrict__ idx, const int* __restrict__ dcount) {
  __shared__ __align__(16) char H[64 * 1024];
  const int tid = threadIdx.x;
  const int lane = tid & 63;
  const int wid = tid >> 6;  // 8 feature-slice waves
  const long abase = (long)blockIdx.x * 64;

  // compacted mode: nvalid atoms in idx[]; surplus blocks exit whole.
  int nvalid = natoms;
  if (idx) {
    nvalid = *dcount;
    if (abase >= nvalid) return;  // uniform whole-block exit (no barrier hazard)
  }

  // ---- stage X[64x256] -> fp16 LDS, pitch 512B, swizzled ----
  {
    const int r = tid >> 3, cg = tid & 7;
    long li = abase + r;
    const long lmax = (long)nvalid - 1;
    if (li > lmax) li = lmax;  // clamp: pad rows read a valid row, never stored
    const long g = idx ? (long)idx[li] : li;
    const float* xp = X + g * 256;
    const int sw = (r & 31) << 4;
#pragma unroll
    for (int j = 0; j < 8; ++j) {
      const int colh = cg * 4 + j * 32;
      f32x4 v = *(const f32x4*)(xp + colh);
      half4 h;
#pragma unroll
      for (int e = 0; e < 4; ++e) h[e] = (_Float16)v[e];
      *(half4*)(H + r * 512 + ((colh * 2) ^ sw)) = h;
    }
  }
  __syncthreads();

  // L1: Xh[64x256] -> H1[64x512]   (8 wfeat x FT=2 -> 512 feats)
  layer<2, 2, 16, 512, 1024>(wt1, b1, H, wid, lane);
  __syncthreads();
  // L2: H1 -> H2[64x512]
  layer<2, 2, 32, 1024, 1024>(wt2, b2, H, wid, lane);
  __syncthreads();
  // L3: H2 -> H3[64x256]           (8 wfeat x FT=1 -> 256 feats)
  layer<1, 2, 32, 1024, 1024>(wt3, b3, H, wid, lane);
  __syncthreads();

  // L4: out[atom] = dot(H3[atom], w4) + b4
  const int atom = tid >> 3, part = tid & 7;
  const int sw = (atom & 31) << 4;
  const char* h3 = H + atom * 1024;
  const _Float16* w4p = w4h + part * 32;
  float sum = 0.0f;
#pragma unroll
  for (int j = 0; j < 4; ++j) {
    half8 h = *(const half8*)(h3 + ((part * 64 + j * 16) ^ sw));
    half8 w = *(const half8*)(w4p + j * 8);
#pragma unroll
    for (int e = 0; e < 8; ++e) sum += (float)h[e] * (float)w[e];
  }
  sum += __shfl_xor(sum, 1);
  sum += __shfl_xor(sum, 2);
  sum += __shfl_xor(sum, 4);
  if (part == 0) {
    const long li = abase + atom;
    if (li < nvalid) {
      float r = sum + b4[0];
      if (idx) {
        out[idx[li]] = r;  // compacted atoms are all valid; masked zeroed in compact
      } else {
        out[li] = (species[li] >= 0) ? r : 0.0f;
      }
    }
  }
}

extern "C" void kernel_launch(void* const* d_in, const int* in_sizes, int n_in,
                              void* d_out, int out_size, void* d_ws, size_t ws_size,
                              hipStream_t stream) {
  const float* X = (const float*)d_in[0];
  const int* species = (const int*)d_in[1];
  const float* W1 = (const float*)d_in[2];
  const float* b1 = (const float*)d_in[3];
  const float* W2 = (const float*)d_in[4];
  const float* b2 = (const float*)d_in[5];
  const float* W3 = (const float*)d_in[6];
  const float* b3 = (const float*)d_in[7];
  const float* W4 = (const float*)d_in[8];
  const float* b4 = (const float*)d_in[9];
  float* out = (float*)d_out;
  const int natoms = in_sizes[0] / 256;  // in_sizes is ELEMENTS (R14 lesson)

  char* ws = (char*)d_ws;
  _Float16* wt1 = (_Float16*)(ws);                             // 512*256*2 B
  _Float16* wt2 = (_Float16*)(ws + 262144);                    // 512*512*2 B
  _Float16* wt3 = (_Float16*)(ws + 262144 + 524288);           // 256*512*2 B
  _Float16* w4h = (_Float16*)(ws + 262144 + 524288 + 262144);  // 512 B
  int* dcount = (int*)(ws + 1049088);                          // 4 B (128-aligned)
  int* didx = (int*)(ws + 1052672);                            // natoms*4 B

  const size_t ws_needed = 1052672 + (size_t)natoms * 4;
  const bool use_compact = (ws_size >= ws_needed);

  const int prep_total = 512 * 256 + 512 * 512 + 256 * 512 + 256;
  hipLaunchKernelGGL(prep_weights, dim3((prep_total + 255) / 256), dim3(256), 0, stream,
                     W1, W2, W3, W4, wt1, wt2, wt3, w4h);

  if (use_compact) {
    hipMemsetAsync(dcount, 0, 4, stream);
    hipLaunchKernelGGL(compact_kernel, dim3((natoms + 255) / 256), dim3(256), 0, stream,
                       species, didx, dcount, out, natoms);
  }

  const int nblocks = (natoms + 63) / 64;  // worst case; surplus blocks exit early
  hipLaunchKernelGGL(mlp_kernel, dim3(nblocks), dim3(512), 0, stream,
                     X, species, wt1, b1, wt2, b2, wt3, b3, w4h, b4, out, natoms,
                     use_compact ? didx : (const int*)nullptr,
                     use_compact ? (const int*)dcount : (const int*)nullptr);
}

// Round 8
// 360.400 us; speedup vs baseline: 1.2740x; 1.1228x over previous
//
#include <hip/hip_runtime.h>

typedef _Float16 half8 __attribute__((ext_vector_type(8)));
typedef _Float16 half4 __attribute__((ext_vector_type(4)));
typedef float f32x4 __attribute__((ext_vector_type(4)));
typedef float f32x16 __attribute__((ext_vector_type(16)));

#define NCHUNK_MAX 2048  // supports up to 524288 atoms in compact mode

// ---------------- prologue: weights retile + chunk-local compaction --------
// One dispatch, two block roles:
//   blocks [0, nprep): cast + retile weights to fp16 MFMA tiles (unchanged).
//   blocks [nprep, nprep+nchunks): chunk c self-compacts its 256 atoms into
//     idxloc[c*256 ...] and writes cnt[c]. NO atomics, NO counter to zero ->
//     no memset dispatch, no separate compact dispatch (R15's +50us overhead).
//     Invalid atoms write out[i]=0 here (must be exactly 0 in the output).
__global__ void prep_compact(const float* __restrict__ W1, const float* __restrict__ W2,
                             const float* __restrict__ W3, const float* __restrict__ W4,
                             _Float16* __restrict__ wt1, _Float16* __restrict__ wt2,
                             _Float16* __restrict__ wt3, _Float16* __restrict__ w4h,
                             const int* __restrict__ species, int* __restrict__ idxloc,
                             int* __restrict__ cnt, float* __restrict__ out,
                             int natoms, int nprep) {
  __shared__ int wsum[4];
  if (blockIdx.x >= nprep) {
    // ---- chunk-local compaction (256 threads = 4 waves) ----
    const int c = blockIdx.x - nprep;
    const int i = c * 256 + threadIdx.x;
    const bool valid = (i < natoms) && (species[i] >= 0);
    const unsigned long long m = __ballot(valid);
    const int lane = threadIdx.x & 63, w = threadIdx.x >> 6;
    if (lane == 0) wsum[w] = (int)__popcll(m);
    __syncthreads();
    int base = 0;
#pragma unroll
    for (int k = 0; k < 4; ++k)
      if (k < w) base += wsum[k];
    if (valid) {
      int off = (int)__popcll(m & ((1ull << lane) - 1));
      idxloc[c * 256 + base + off] = i;
    } else if (i < natoms) {
      out[i] = 0.0f;  // masked atoms must be exactly 0
    }
    if (threadIdx.x == 0) cnt[c] = wsum[0] + wsum[1] + wsum[2] + wsum[3];
    return;
  }
  // ---- weight retile (unchanged math) ----
  int idx = blockIdx.x * blockDim.x + threadIdx.x;
  if (idx < 512 * 256) {  // W1: K=256, N=512, KS=16
    int k = idx >> 9, n = idx & 511;
    int off = (((n >> 5) * 16 + (k >> 4)) << 9) + (n & 31) * 8 + (((k >> 3) & 1) << 8) + (k & 7);
    wt1[off] = (_Float16)W1[idx];
    return;
  }
  int i2 = idx - 512 * 256;
  if (i2 < 512 * 512) {  // W2: K=512, N=512, KS=32
    int k = i2 >> 9, n = i2 & 511;
    int off = (((n >> 5) * 32 + (k >> 4)) << 9) + (n & 31) * 8 + (((k >> 3) & 1) << 8) + (k & 7);
    wt2[off] = (_Float16)W2[i2];
    return;
  }
  int i3 = i2 - 512 * 512;
  if (i3 < 512 * 256) {  // W3: K=512, N=256, KS=32
    int k = i3 >> 8, n = i3 & 255;
    int off = (((n >> 5) * 32 + (k >> 4)) << 9) + (n & 31) * 8 + (((k >> 3) & 1) << 8) + (k & 7);
    wt3[off] = (_Float16)W3[i3];
    return;
  }
  int i4 = i3 - 512 * 256;
  if (i4 < 256) w4h[i4] = (_Float16)W4[i4];
}

// silu with raw v_rcp_f32 (no IEEE div sequence); ~1ulp, well within tolerance
__device__ __forceinline__ float fast_silu(float s) {
  float e = __expf(-s);
  float d = 1.0f + e;
  float r;
  asm("v_rcp_f32 %0, %1" : "=v"(r) : "v"(d));
  return s * r;
}

// ---------------- fused MLP ----------------
// R8 geometry (verified local optimum): 64 atoms/block, 512 threads = 8
// waves, FT=2, AT=2, acc 64 AGPR + 64 arch VGPR = exactly the 128-reg
// budget at 4 waves/EU; 2 blocks/CU -> 16 waves/CU in TWO independent
// barrier domains (R13: merging them costs 16%).
// Evidence: R9 FAILED (L3 prefetch thrash). R10 NEUTRAL (bias-fold + pre-
// barrier silu; kept). R11 falsified skew. R12 falsified 8 waves/CU. R13
// falsified single-domain pairing. R14 FAILED (in_sizes is elements).
// R15: compaction works (mlp -10%, counters work-proportional) but the 2
// extra dispatches cost ~50us on the bench -> R16 makes compaction
// dispatch-free: chunk-local compact in prep (no atomics), and each mlp
// block prefix-scans cnt[] (4.7KB, ~1-2us) to locate its atom window.

#define MFMA(a, b, c) __builtin_amdgcn_mfma_f32_32x32x16_f16(a, b, c, 0, 0, 0)

template <int FT, int AT, int KS, int PIN, int POUT>
__device__ __forceinline__ void layer(const _Float16* __restrict__ wt,
                                      const float* __restrict__ bias,
                                      char* __restrict__ Hb,
                                      int wfeat, int lane) {
  const int lr = lane & 31;
  const int lh = lane >> 5;
  const int n0 = wfeat * (FT * 32);
  const int s0 = (lr & 31) << 4;  // row swizzle; (a*32+lr)&31 == lr&31
  const char* Bp = Hb + lr * PIN;
  const char* wp = (const char*)wt + (size_t)(wfeat * FT * KS) * 1024 + lh * 512 + lr * 16;

  // init acc = bias (folds epilogue bias-add into MFMA C-in; bv transient)
  f32x16 acc[FT][AT];
#pragma unroll
  for (int f = 0; f < FT; ++f)
#pragma unroll
    for (int rg = 0; rg < 4; ++rg) {
      const int feat = n0 + f * 32 + rg * 8 + lh * 4;
      const f32x4 bv = *(const f32x4*)(bias + feat);
#pragma unroll
      for (int a = 0; a < AT; ++a)
#pragma unroll
        for (int r = 0; r < 4; ++r) acc[f][a][rg * 4 + r] = bv[r];
    }

  half8 Af[FT], Ag[FT], Bf[AT], Bg[AT];
#pragma unroll
  for (int f = 0; f < FT; ++f) Af[f] = *(const half8*)(wp + f * (KS * 1024));
#pragma unroll
  for (int a = 0; a < AT; ++a)
    Bf[a] = *(const half8*)(Bp + a * 32 * PIN + ((lh * 16) ^ s0));

#pragma unroll 1
  for (int ks = 0; ks < KS - 2; ks += 2) {
    // prefetch ks+1 into g-buffers
#pragma unroll
    for (int f = 0; f < FT; ++f)
      Ag[f] = *(const half8*)(wp + f * (KS * 1024) + (ks + 1) * 1024);
#pragma unroll
    for (int a = 0; a < AT; ++a)
      Bg[a] = *(const half8*)(Bp + a * 32 * PIN + (((ks + 1) * 32 + lh * 16) ^ s0));
    // compute ks
#pragma unroll
    for (int f = 0; f < FT; ++f)
#pragma unroll
      for (int a = 0; a < AT; ++a) acc[f][a] = MFMA(Af[f], Bf[a], acc[f][a]);
    // prefetch ks+2 into f-buffers
#pragma unroll
    for (int f = 0; f < FT; ++f)
      Af[f] = *(const half8*)(wp + f * (KS * 1024) + (ks + 2) * 1024);
#pragma unroll
    for (int a = 0; a < AT; ++a)
      Bf[a] = *(const half8*)(Bp + a * 32 * PIN + (((ks + 2) * 32 + lh * 16) ^ s0));
    // compute ks+1
#pragma unroll
    for (int f = 0; f < FT; ++f)
#pragma unroll
      for (int a = 0; a < AT; ++a) acc[f][a] = MFMA(Ag[f], Bg[a], acc[f][a]);
  }
  // tail: ks = KS-2 in f-buffers; prefetch KS-1; compute both
#pragma unroll
  for (int f = 0; f < FT; ++f)
    Ag[f] = *(const half8*)(wp + f * (KS * 1024) + (KS - 1) * 1024);
#pragma unroll
  for (int a = 0; a < AT; ++a)
    Bg[a] = *(const half8*)(Bp + a * 32 * PIN + ((((KS - 1) * 32) + lh * 16) ^ s0));
#pragma unroll
  for (int f = 0; f < FT; ++f)
#pragma unroll
    for (int a = 0; a < AT; ++a) acc[f][a] = MFMA(Af[f], Bf[a], acc[f][a]);
#pragma unroll
  for (int f = 0; f < FT; ++f)
#pragma unroll
    for (int a = 0; a < AT; ++a) acc[f][a] = MFMA(Ag[f], Bg[a], acc[f][a]);

  // silu in-place on private accumulators — BEFORE the barrier (R10).
#pragma unroll
  for (int f = 0; f < FT; ++f)
#pragma unroll
    for (int a = 0; a < AT; ++a)
#pragma unroll
      for (int j = 0; j < 16; ++j) acc[f][a][j] = fast_silu(acc[f][a][j]);

  __syncthreads();  // all waves finished reading input region; safe to overwrite

  // post-barrier: cvt -> fp16, write swizzled (2-way, free)
#pragma unroll
  for (int f = 0; f < FT; ++f) {
#pragma unroll
    for (int rg = 0; rg < 4; ++rg) {
      const int feat = n0 + f * 32 + rg * 8 + lh * 4;
#pragma unroll
      for (int a = 0; a < AT; ++a) {
        half4 h;
#pragma unroll
        for (int r = 0; r < 4; ++r) h[r] = (_Float16)acc[f][a][rg * 4 + r];
        const int row = a * 32 + lr;
        *(half4*)(Hb + row * POUT + ((feat * 2) ^ ((row & 31) << 4))) = h;
      }
    }
  }
}

extern "C" __global__ void __launch_bounds__(512, 4)
mlp_kernel(const float* __restrict__ X, const int* __restrict__ species,
           const _Float16* __restrict__ wt1, const float* __restrict__ b1,
           const _Float16* __restrict__ wt2, const float* __restrict__ b2,
           const _Float16* __restrict__ wt3, const float* __restrict__ b3,
           const _Float16* __restrict__ w4h, const float* __restrict__ b4,
           float* __restrict__ out, int natoms,
           const int* __restrict__ idxloc, const int* __restrict__ cnt, int nchunks) {
  __shared__ __align__(16) char H[64 * 1024];
  __shared__ int prefixS[NCHUNK_MAX + 1];  // exclusive chunk starts
  __shared__ int gidx[64];                 // source atom per staged row
  __shared__ int wtot[8];
  const int tid = threadIdx.x;
  const int lane = tid & 63;
  const int wid = tid >> 6;  // 8 feature-slice waves
  const long abase = (long)blockIdx.x * 64;

  int nvalid = natoms;
  if (idxloc) {
    // ---- per-block prefix scan of cnt[] (two-level, 512 threads) ----
    int v[4];
    int tsum = 0;
#pragma unroll
    for (int j = 0; j < 4; ++j) {
      const int c = tid * 4 + j;
      v[j] = (c < nchunks) ? cnt[c] : 0;
      tsum += v[j];
    }
    int ws_ = tsum;
#pragma unroll
    for (int d = 1; d < 64; d <<= 1) {
      int o = __shfl_up(ws_, d);
      if (lane >= d) ws_ += o;
    }
    if (lane == 63) wtot[wid] = ws_;
    __syncthreads();
    int wbase = 0, tot = 0;
#pragma unroll
    for (int k = 0; k < 8; ++k) {
      if (k < wid) wbase += wtot[k];
      tot += wtot[k];
    }
    int run = wbase + ws_ - tsum;  // exclusive prefix for this thread's chunks
#pragma unroll
    for (int j = 0; j < 4; ++j) {
      const int c = tid * 4 + j;
      if (c < nchunks) prefixS[c] = run;
      run += v[j];
    }
    if (tid == 0) prefixS[nchunks] = tot;
    nvalid = tot;
    __syncthreads();  // prefixS ready before staging reads it
    if (abase >= nvalid) return;  // uniform whole-block exit
  }

  // ---- stage X[64x256] -> fp16 LDS, pitch 512B, swizzled ----
  {
    const int r = tid >> 3, cg = tid & 7;
    long li = abase + r;
    const long lmax = (long)nvalid - 1;
    if (li > lmax) li = lmax;  // clamp: pad rows read a valid row, never stored
    long g = li;
    if (idxloc) {
      // binary search: largest c with prefixS[c] <= li
      int lo = 0, hi = nchunks - 1;
      while (lo < hi) {
        int mid = (lo + hi + 1) >> 1;
        if (prefixS[mid] <= (int)li) lo = mid; else hi = mid - 1;
      }
      g = idxloc[lo * 256 + ((int)li - prefixS[lo])];
      if (cg == 0) gidx[r] = (int)g;
    }
    const float* xp = X + g * 256;
    const int sw = (r & 31) << 4;
#pragma unroll
    for (int j = 0; j < 8; ++j) {
      const int colh = cg * 4 + j * 32;
      f32x4 v = *(const f32x4*)(xp + colh);
      half4 h;
#pragma unroll
      for (int e = 0; e < 4; ++e) h[e] = (_Float16)v[e];
      *(half4*)(H + r * 512 + ((colh * 2) ^ sw)) = h;
    }
  }
  __syncthreads();

  // L1: Xh[64x256] -> H1[64x512]   (8 wfeat x FT=2 -> 512 feats)
  layer<2, 2, 16, 512, 1024>(wt1, b1, H, wid, lane);
  __syncthreads();
  // L2: H1 -> H2[64x512]
  layer<2, 2, 32, 1024, 1024>(wt2, b2, H, wid, lane);
  __syncthreads();
  // L3: H2 -> H3[64x256]           (8 wfeat x FT=1 -> 256 feats)
  layer<1, 2, 32, 1024, 1024>(wt3, b3, H, wid, lane);
  __syncthreads();

  // L4: out[atom] = dot(H3[atom], w4) + b4
  const int atom = tid >> 3, part = tid & 7;
  const int sw = (atom & 31) << 4;
  const char* h3 = H + atom * 1024;
  const _Float16* w4p = w4h + part * 32;
  float sum = 0.0f;
#pragma unroll
  for (int j = 0; j < 4; ++j) {
    half8 h = *(const half8*)(h3 + ((part * 64 + j * 16) ^ sw));
    half8 w = *(const half8*)(w4p + j * 8);
#pragma unroll
    for (int e = 0; e < 8; ++e) sum += (float)h[e] * (float)w[e];
  }
  sum += __shfl_xor(sum, 1);
  sum += __shfl_xor(sum, 2);
  sum += __shfl_xor(sum, 4);
  if (part == 0) {
    const long li = abase + atom;
    if (li < nvalid) {
      float r = sum + b4[0];
      if (idxloc) {
        out[gidx[atom]] = r;  // compacted atoms all valid; masked zeroed in prep
      } else {
        out[li] = (species[li] >= 0) ? r : 0.0f;
      }
    }
  }
}

extern "C" void kernel_launch(void* const* d_in, const int* in_sizes, int n_in,
                              void* d_out, int out_size, void* d_ws, size_t ws_size,
                              hipStream_t stream) {
  const float* X = (const float*)d_in[0];
  const int* species = (const int*)d_in[1];
  const float* W1 = (const float*)d_in[2];
  const float* b1 = (const float*)d_in[3];
  const float* W2 = (const float*)d_in[4];
  const float* b2 = (const float*)d_in[5];
  const float* W3 = (const float*)d_in[6];
  const float* b3 = (const float*)d_in[7];
  const float* W4 = (const float*)d_in[8];
  const float* b4 = (const float*)d_in[9];
  float* out = (float*)d_out;
  const int natoms = in_sizes[0] / 256;  // in_sizes is ELEMENTS (R14 lesson)

  char* ws = (char*)d_ws;
  _Float16* wt1 = (_Float16*)(ws);                             // 512*256*2 B
  _Float16* wt2 = (_Float16*)(ws + 262144);                    // 512*512*2 B
  _Float16* wt3 = (_Float16*)(ws + 262144 + 524288);           // 256*512*2 B
  _Float16* w4h = (_Float16*)(ws + 262144 + 524288 + 262144);  // 512 B
  int* cnt = (int*)(ws + 1049088);                             // nchunks*4 B
  int* idxloc = (int*)(ws + 1049088 + 8192);                   // natoms*4 B

  const int nchunks = (natoms + 255) / 256;
  const size_t ws_needed = 1049088 + 8192 + (size_t)natoms * 4;
  const bool use_compact = (ws_size >= ws_needed) && (nchunks <= NCHUNK_MAX);

  const int prep_total = 512 * 256 + 512 * 512 + 256 * 512 + 256;
  const int nprep = (prep_total + 255) / 256;
  const int nblk = nprep + (use_compact ? nchunks : 0);
  hipLaunchKernelGGL(prep_compact, dim3(nblk), dim3(256), 0, stream,
                     W1, W2, W3, W4, wt1, wt2, wt3, w4h,
                     species, idxloc, cnt, out, natoms, nprep);

  const int nblocks = (natoms + 63) / 64;  // worst case; surplus blocks exit early
  hipLaunchKernelGGL(mlp_kernel, dim3(nblocks), dim3(512), 0, stream,
                     X, species, wt1, b1, wt2, b2, wt3, b3, w4h, b4, out, natoms,
                     use_compact ? idxloc : (const int*)nullptr,
                     use_compact ? (const int*)cnt : (const int*)nullptr, nchunks);
}

// Round 9
// 352.596 us; speedup vs baseline: 1.3022x; 1.0221x over previous
//
#include <hip/hip_runtime.h>

typedef _Float16 half8 __attribute__((ext_vector_type(8)));
typedef _Float16 half4 __attribute__((ext_vector_type(4)));
typedef float f32x4 __attribute__((ext_vector_type(4)));
typedef float f32x16 __attribute__((ext_vector_type(16)));

#define CHUNK 1024
#define NCHUNK_MAX 512  // supports up to 524288 atoms in compact mode

// ---------------- prologue: weights retile + chunk-local compaction --------
// One dispatch, two block roles:
//   blocks [0, nprep): cast + retile weights to fp16 MFMA tiles.
//   blocks [nprep, nprep+nchunks): chunk c (1024 atoms) self-compacts into
//     idxloc[c*1024 ...] and writes cnt[c]. No atomics -> no memset, no
//     extra dispatch (R15: each dispatch costs ~25us on this bench).
//     Chunk-internal order is irrelevant. Invalid atoms write out[i]=0 here.
__global__ void prep_compact(const float* __restrict__ W1, const float* __restrict__ W2,
                             const float* __restrict__ W3, const float* __restrict__ W4,
                             _Float16* __restrict__ wt1, _Float16* __restrict__ wt2,
                             _Float16* __restrict__ wt3, _Float16* __restrict__ w4h,
                             const int* __restrict__ species, int* __restrict__ idxloc,
                             int* __restrict__ cnt, float* __restrict__ out,
                             int natoms, int nprep) {
  __shared__ int wsum[4];
  if (blockIdx.x >= nprep) {
    // ---- chunk-local compaction: 1024 atoms, 256 threads, 4 sub-rounds ----
    const int c = blockIdx.x - nprep;
    const int lane = threadIdx.x & 63, w = threadIdx.x >> 6;
    int base = 0;
#pragma unroll 1
    for (int j = 0; j < 4; ++j) {
      const int i = c * CHUNK + j * 256 + threadIdx.x;
      const bool valid = (i < natoms) && (species[i] >= 0);
      const unsigned long long m = __ballot(valid);
      if (lane == 0) wsum[w] = (int)__popcll(m);
      __syncthreads();
      int wb = base;
#pragma unroll
      for (int k = 0; k < 4; ++k)
        if (k < w) wb += wsum[k];
      if (valid) {
        int off = (int)__popcll(m & ((1ull << lane) - 1));
        idxloc[c * CHUNK + wb + off] = i;
      } else if (i < natoms) {
        out[i] = 0.0f;  // masked atoms must be exactly 0
      }
      base += wsum[0] + wsum[1] + wsum[2] + wsum[3];
      __syncthreads();  // wsum reused next round
    }
    if (threadIdx.x == 0) cnt[c] = base;
    return;
  }
  // ---- weight retile (unchanged math) ----
  int idx = blockIdx.x * blockDim.x + threadIdx.x;
  if (idx < 512 * 256) {  // W1: K=256, N=512, KS=16
    int k = idx >> 9, n = idx & 511;
    int off = (((n >> 5) * 16 + (k >> 4)) << 9) + (n & 31) * 8 + (((k >> 3) & 1) << 8) + (k & 7);
    wt1[off] = (_Float16)W1[idx];
    return;
  }
  int i2 = idx - 512 * 256;
  if (i2 < 512 * 512) {  // W2: K=512, N=512, KS=32
    int k = i2 >> 9, n = i2 & 511;
    int off = (((n >> 5) * 32 + (k >> 4)) << 9) + (n & 31) * 8 + (((k >> 3) & 1) << 8) + (k & 7);
    wt2[off] = (_Float16)W2[i2];
    return;
  }
  int i3 = i2 - 512 * 512;
  if (i3 < 512 * 256) {  // W3: K=512, N=256, KS=32
    int k = i3 >> 8, n = i3 & 255;
    int off = (((n >> 5) * 32 + (k >> 4)) << 9) + (n & 31) * 8 + (((k >> 3) & 1) << 8) + (k & 7);
    wt3[off] = (_Float16)W3[i3];
    return;
  }
  int i4 = i3 - 512 * 256;
  if (i4 < 256) w4h[i4] = (_Float16)W4[i4];
}

// silu with raw v_rcp_f32 (no IEEE div sequence); ~1ulp, well within tolerance
__device__ __forceinline__ float fast_silu(float s) {
  float e = __expf(-s);
  float d = 1.0f + e;
  float r;
  asm("v_rcp_f32 %0, %1" : "=v"(r) : "v"(d));
  return s * r;
}

// ---------------- fused MLP ----------------
// R8 geometry (verified local optimum): 64 atoms/block, 512 threads = 8
// waves, FT=2, AT=2, acc 64 AGPR + 64 arch VGPR = exactly the 128-reg
// budget at 4 waves/EU; 2 blocks/CU -> 16 waves/CU in TWO independent
// barrier domains (R13: merging them costs 16%).
// Evidence: R9 FAILED (L3 prefetch thrash). R10 NEUTRAL (bias-fold + pre-
// barrier silu; kept). R11 falsified skew. R12 falsified 8 waves/CU. R13
// falsified single-domain pairing. R14 FAILED (in_sizes is elements).
// R15: compaction real but 2 extra dispatches cost ~50us. R16 WIN (360us):
// dispatch-free compaction + per-block scan.
// R17 (this round): (a) CHUNK 256->1024: scan/search cost /4 (293 ints);
// (b) L4 merged into L3's register epilogue: after L3 silu each wave holds
// H3 feats [wid*32,+32) for all 64 atoms in acc -> dot with w4 slice in-
// register (16 FMA + shfl_xor(32)), write 8x64 f32 partials into dead H,
// one tiny reduce. Deletes H3 cvt+32KB store and L4's 32KB re-read.

#define MFMA(a, b, c) __builtin_amdgcn_mfma_f32_32x32x16_f16(a, b, c, 0, 0, 0)

template <int FT, int AT, int KS, int PIN, int POUT>
__device__ __forceinline__ void layer(const _Float16* __restrict__ wt,
                                      const float* __restrict__ bias,
                                      char* __restrict__ Hb,
                                      int wfeat, int lane) {
  const int lr = lane & 31;
  const int lh = lane >> 5;
  const int n0 = wfeat * (FT * 32);
  const int s0 = (lr & 31) << 4;  // row swizzle; (a*32+lr)&31 == lr&31
  const char* Bp = Hb + lr * PIN;
  const char* wp = (const char*)wt + (size_t)(wfeat * FT * KS) * 1024 + lh * 512 + lr * 16;

  // init acc = bias (folds epilogue bias-add into MFMA C-in; bv transient)
  f32x16 acc[FT][AT];
#pragma unroll
  for (int f = 0; f < FT; ++f)
#pragma unroll
    for (int rg = 0; rg < 4; ++rg) {
      const int feat = n0 + f * 32 + rg * 8 + lh * 4;
      const f32x4 bv = *(const f32x4*)(bias + feat);
#pragma unroll
      for (int a = 0; a < AT; ++a)
#pragma unroll
        for (int r = 0; r < 4; ++r) acc[f][a][rg * 4 + r] = bv[r];
    }

  half8 Af[FT], Ag[FT], Bf[AT], Bg[AT];
#pragma unroll
  for (int f = 0; f < FT; ++f) Af[f] = *(const half8*)(wp + f * (KS * 1024));
#pragma unroll
  for (int a = 0; a < AT; ++a)
    Bf[a] = *(const half8*)(Bp + a * 32 * PIN + ((lh * 16) ^ s0));

#pragma unroll 1
  for (int ks = 0; ks < KS - 2; ks += 2) {
#pragma unroll
    for (int f = 0; f < FT; ++f)
      Ag[f] = *(const half8*)(wp + f * (KS * 1024) + (ks + 1) * 1024);
#pragma unroll
    for (int a = 0; a < AT; ++a)
      Bg[a] = *(const half8*)(Bp + a * 32 * PIN + (((ks + 1) * 32 + lh * 16) ^ s0));
#pragma unroll
    for (int f = 0; f < FT; ++f)
#pragma unroll
      for (int a = 0; a < AT; ++a) acc[f][a] = MFMA(Af[f], Bf[a], acc[f][a]);
#pragma unroll
    for (int f = 0; f < FT; ++f)
      Af[f] = *(const half8*)(wp + f * (KS * 1024) + (ks + 2) * 1024);
#pragma unroll
    for (int a = 0; a < AT; ++a)
      Bf[a] = *(const half8*)(Bp + a * 32 * PIN + (((ks + 2) * 32 + lh * 16) ^ s0));
#pragma unroll
    for (int f = 0; f < FT; ++f)
#pragma unroll
      for (int a = 0; a < AT; ++a) acc[f][a] = MFMA(Ag[f], Bg[a], acc[f][a]);
  }
#pragma unroll
  for (int f = 0; f < FT; ++f)
    Ag[f] = *(const half8*)(wp + f * (KS * 1024) + (KS - 1) * 1024);
#pragma unroll
  for (int a = 0; a < AT; ++a)
    Bg[a] = *(const half8*)(Bp + a * 32 * PIN + ((((KS - 1) * 32) + lh * 16) ^ s0));
#pragma unroll
  for (int f = 0; f < FT; ++f)
#pragma unroll
    for (int a = 0; a < AT; ++a) acc[f][a] = MFMA(Af[f], Bf[a], acc[f][a]);
#pragma unroll
  for (int f = 0; f < FT; ++f)
#pragma unroll
    for (int a = 0; a < AT; ++a) acc[f][a] = MFMA(Ag[f], Bg[a], acc[f][a]);

  // silu in-place BEFORE the barrier (R10).
#pragma unroll
  for (int f = 0; f < FT; ++f)
#pragma unroll
    for (int a = 0; a < AT; ++a)
#pragma unroll
      for (int j = 0; j < 16; ++j) acc[f][a][j] = fast_silu(acc[f][a][j]);

  __syncthreads();  // all waves done reading input region; safe to overwrite

  // post-barrier: cvt -> fp16, write swizzled (2-way, free)
#pragma unroll
  for (int f = 0; f < FT; ++f) {
#pragma unroll
    for (int rg = 0; rg < 4; ++rg) {
      const int feat = n0 + f * 32 + rg * 8 + lh * 4;
#pragma unroll
      for (int a = 0; a < AT; ++a) {
        half4 h;
#pragma unroll
        for (int r = 0; r < 4; ++r) h[r] = (_Float16)acc[f][a][rg * 4 + r];
        const int row = a * 32 + lr;
        *(half4*)(Hb + row * POUT + ((feat * 2) ^ ((row & 31) << 4))) = h;
      }
    }
  }
}

extern "C" __global__ void __launch_bounds__(512, 4)
mlp_kernel(const float* __restrict__ X, const int* __restrict__ species,
           const _Float16* __restrict__ wt1, const float* __restrict__ b1,
           const _Float16* __restrict__ wt2, const float* __restrict__ b2,
           const _Float16* __restrict__ wt3, const float* __restrict__ b3,
           const _Float16* __restrict__ w4h, const float* __restrict__ b4,
           float* __restrict__ out, int natoms,
           const int* __restrict__ idxloc, const int* __restrict__ cnt, int nchunks) {
  __shared__ __align__(16) char H[64 * 1024];
  __shared__ int prefixS[NCHUNK_MAX + 1];  // exclusive chunk starts
  __shared__ int gidx[64];                 // source atom per staged row
  __shared__ int wtot[8];
  const int tid = threadIdx.x;
  const int lane = tid & 63;
  const int wid = tid >> 6;  // 8 feature-slice waves
  const long abase = (long)blockIdx.x * 64;

  int nvalid = natoms;
  if (idxloc) {
    // ---- per-block prefix scan of cnt[] (nchunks <= 512, 1 per thread) ----
    int v = (tid < nchunks) ? cnt[tid] : 0;
    int ws_ = v;
#pragma unroll
    for (int d = 1; d < 64; d <<= 1) {
      int o = __shfl_up(ws_, d);
      if (lane >= d) ws_ += o;
    }
    if (lane == 63) wtot[wid] = ws_;
    __syncthreads();
    int wbase = 0, tot = 0;
#pragma unroll
    for (int k = 0; k < 8; ++k) {
      if (k < wid) wbase += wtot[k];
      tot += wtot[k];
    }
    if (tid < nchunks) prefixS[tid] = wbase + ws_ - v;  // exclusive
    nvalid = tot;
    __syncthreads();  // prefixS ready
    if (abase >= nvalid) return;  // uniform whole-block exit
  }

  // ---- stage X[64x256] -> fp16 LDS, pitch 512B, swizzled ----
  {
    const int r = tid >> 3, cg = tid & 7;
    long li = abase + r;
    const long lmax = (long)nvalid - 1;
    if (li > lmax) li = lmax;  // clamp: pad rows read a valid row, never stored
    long g = li;
    if (idxloc) {
      int lo = 0, hi = nchunks - 1;  // largest c with prefixS[c] <= li
      while (lo < hi) {
        int mid = (lo + hi + 1) >> 1;
        if (prefixS[mid] <= (int)li) lo = mid; else hi = mid - 1;
      }
      g = idxloc[lo * CHUNK + ((int)li - prefixS[lo])];
      if (cg == 0) gidx[r] = (int)g;
    }
    const float* xp = X + g * 256;
    const int sw = (r & 31) << 4;
#pragma unroll
    for (int j = 0; j < 8; ++j) {
      const int colh = cg * 4 + j * 32;
      f32x4 v = *(const f32x4*)(xp + colh);
      half4 h;
#pragma unroll
      for (int e = 0; e < 4; ++e) h[e] = (_Float16)v[e];
      *(half4*)(H + r * 512 + ((colh * 2) ^ sw)) = h;
    }
  }
  __syncthreads();

  // L1: Xh[64x256] -> H1[64x512]   (8 wfeat x FT=2 -> 512 feats)
  layer<2, 2, 16, 512, 1024>(wt1, b1, H, wid, lane);
  __syncthreads();
  // L2: H1 -> H2[64x512]
  layer<2, 2, 32, 1024, 1024>(wt2, b2, H, wid, lane);
  __syncthreads();

  // ---- L3 (FT=1, AT=2, KS=32) with L4 fused into the register epilogue ----
  {
    const int lr = lane & 31;
    const int lh = lane >> 5;
    const int n0 = wid * 32;
    const int s0 = (lr & 31) << 4;
    const char* Bp = H + lr * 1024;
    const char* wp = (const char*)wt3 + (size_t)(wid * 32) * 1024 + lh * 512 + lr * 16;

    f32x16 acc[2];
#pragma unroll
    for (int rg = 0; rg < 4; ++rg) {
      const int feat = n0 + rg * 8 + lh * 4;
      const f32x4 bv = *(const f32x4*)(b3 + feat);
#pragma unroll
      for (int a = 0; a < 2; ++a)
#pragma unroll
        for (int r = 0; r < 4; ++r) acc[a][rg * 4 + r] = bv[r];
    }

    half8 Af, Ag, Bf[2], Bg[2];
    Af = *(const half8*)(wp);
#pragma unroll
    for (int a = 0; a < 2; ++a)
      Bf[a] = *(const half8*)(Bp + a * 32 * 1024 + ((lh * 16) ^ s0));

#pragma unroll 1
    for (int ks = 0; ks < 30; ks += 2) {
      Ag = *(const half8*)(wp + (ks + 1) * 1024);
#pragma unroll
      for (int a = 0; a < 2; ++a)
        Bg[a] = *(const half8*)(Bp + a * 32 * 1024 + (((ks + 1) * 32 + lh * 16) ^ s0));
#pragma unroll
      for (int a = 0; a < 2; ++a) acc[a] = MFMA(Af, Bf[a], acc[a]);
      Af = *(const half8*)(wp + (ks + 2) * 1024);
#pragma unroll
      for (int a = 0; a < 2; ++a)
        Bf[a] = *(const half8*)(Bp + a * 32 * 1024 + (((ks + 2) * 32 + lh * 16) ^ s0));
#pragma unroll
      for (int a = 0; a < 2; ++a) acc[a] = MFMA(Ag, Bg[a], acc[a]);
    }
    Ag = *(const half8*)(wp + 31 * 1024);
#pragma unroll
    for (int a = 0; a < 2; ++a)
      Bg[a] = *(const half8*)(Bp + a * 32 * 1024 + ((31 * 32 + lh * 16) ^ s0));
#pragma unroll
    for (int a = 0; a < 2; ++a) acc[a] = MFMA(Af, Bf[a], acc[a]);
#pragma unroll
    for (int a = 0; a < 2; ++a) acc[a] = MFMA(Ag, Bg[a], acc[a]);

    // silu + in-register dot with w4 slice (feats n0+rg*8+lh*4+r)
    float s[2] = {0.0f, 0.0f};
#pragma unroll
    for (int rg = 0; rg < 4; ++rg) {
      half4 wv = *(const half4*)(w4h + n0 + rg * 8 + lh * 4);
#pragma unroll
      for (int r = 0; r < 4; ++r) {
        const float wf = (float)wv[r];
#pragma unroll
        for (int a = 0; a < 2; ++a)
          s[a] += fast_silu(acc[a][rg * 4 + r]) * wf;
      }
    }
    // combine the two feat-halves (lh=0/1) held by lanes lr and lr+32
    s[0] += __shfl_xor(s[0], 32);
    s[1] += __shfl_xor(s[1], 32);

    __syncthreads();  // all waves done reading H2 -> safe to overwrite with P
    float* P = (float*)H;  // P[atom][8] partials, 2KB
    if (lh == 0) {
      P[(0 * 32 + lr) * 8 + wid] = s[0];
      P[(1 * 32 + lr) * 8 + wid] = s[1];
    }
  }
  __syncthreads();

  // final reduce: out[atom] = sum_w P[atom][w] + b4
  {
    const float* P = (const float*)H;
    const int atom = tid >> 3, part = tid & 7;
    float sum = P[atom * 8 + part];
    sum += __shfl_xor(sum, 1);
    sum += __shfl_xor(sum, 2);
    sum += __shfl_xor(sum, 4);
    if (part == 0) {
      const long li = abase + atom;
      if (li < nvalid) {
        float r = sum + b4[0];
        if (idxloc) {
          out[gidx[atom]] = r;  // masked atoms zeroed in prep
        } else {
          out[li] = (species[li] >= 0) ? r : 0.0f;
        }
      }
    }
  }
}

extern "C" void kernel_launch(void* const* d_in, const int* in_sizes, int n_in,
                              void* d_out, int out_size, void* d_ws, size_t ws_size,
                              hipStream_t stream) {
  const float* X = (const float*)d_in[0];
  const int* species = (const int*)d_in[1];
  const float* W1 = (const float*)d_in[2];
  const float* b1 = (const float*)d_in[3];
  const float* W2 = (const float*)d_in[4];
  const float* b2 = (const float*)d_in[5];
  const float* W3 = (const float*)d_in[6];
  const float* b3 = (const float*)d_in[7];
  const float* W4 = (const float*)d_in[8];
  const float* b4 = (const float*)d_in[9];
  float* out = (float*)d_out;
  const int natoms = in_sizes[0] / 256;  // in_sizes is ELEMENTS (R14 lesson)

  char* ws = (char*)d_ws;
  _Float16* wt1 = (_Float16*)(ws);                             // 512*256*2 B
  _Float16* wt2 = (_Float16*)(ws + 262144);                    // 512*512*2 B
  _Float16* wt3 = (_Float16*)(ws + 262144 + 524288);           // 256*512*2 B
  _Float16* w4h = (_Float16*)(ws + 262144 + 524288 + 262144);  // 512 B
  int* cnt = (int*)(ws + 1049088);                             // nchunks*4 B
  int* idxloc = (int*)(ws + 1049088 + 4096);                   // natoms*4 B (padded region)

  const int nchunks = (natoms + CHUNK - 1) / CHUNK;
  const size_t ws_needed = 1049088 + 4096 + (size_t)nchunks * CHUNK * 4;
  const bool use_compact = (ws_size >= ws_needed) && (nchunks <= NCHUNK_MAX);

  const int prep_total = 512 * 256 + 512 * 512 + 256 * 512 + 256;
  const int nprep = (prep_total + 255) / 256;
  const int nblk = nprep + (use_compact ? nchunks : 0);
  hipLaunchKernelGGL(prep_compact, dim3(nblk), dim3(256), 0, stream,
                     W1, W2, W3, W4, wt1, wt2, wt3, w4h,
                     species, idxloc, cnt, out, natoms, nprep);

  const int nblocks = (natoms + 63) / 64;  // worst case; surplus blocks exit early
  hipLaunchKernelGGL(mlp_kernel, dim3(nblocks), dim3(512), 0, stream,
                     X, species, wt1, b1, wt2, b2, wt3, b3, w4h, b4, out, natoms,
                     use_compact ? idxloc : (const int*)nullptr,
                     use_compact ? (const int*)cnt : (const int*)nullptr, nchunks);
}

// Round 10
// 350.291 us; speedup vs baseline: 1.3108x; 1.0066x over previous
//
#include <hip/hip_runtime.h>

typedef _Float16 half8 __attribute__((ext_vector_type(8)));
typedef _Float16 half4 __attribute__((ext_vector_type(4)));
typedef float f32x4 __attribute__((ext_vector_type(4)));
typedef float f32x16 __attribute__((ext_vector_type(16)));

#define CHUNK 1024
#define NCHUNK_MAX 512  // supports up to 524288 atoms in compact mode

// ---------------- prologue: weights retile + chunk-local compaction --------
// One dispatch, two block roles:
//   blocks [0, nprep): cast + retile weights to fp16 MFMA tiles.
//   blocks [nprep, nprep+nchunks): chunk c (1024 atoms) self-compacts into
//     idxloc[c*1024 ...] and writes cnt[c]. No atomics -> no memset, no
//     extra dispatch (R15: each dispatch costs ~25us on this bench).
__global__ void prep_compact(const float* __restrict__ W1, const float* __restrict__ W2,
                             const float* __restrict__ W3, const float* __restrict__ W4,
                             _Float16* __restrict__ wt1, _Float16* __restrict__ wt2,
                             _Float16* __restrict__ wt3, _Float16* __restrict__ w4h,
                             const int* __restrict__ species, int* __restrict__ idxloc,
                             int* __restrict__ cnt, float* __restrict__ out,
                             int natoms, int nprep) {
  __shared__ int wsum[4];
  if (blockIdx.x >= nprep) {
    // ---- chunk-local compaction: 1024 atoms, 256 threads, 4 sub-rounds ----
    const int c = blockIdx.x - nprep;
    const int lane = threadIdx.x & 63, w = threadIdx.x >> 6;
    int base = 0;
#pragma unroll 1
    for (int j = 0; j < 4; ++j) {
      const int i = c * CHUNK + j * 256 + threadIdx.x;
      const bool valid = (i < natoms) && (species[i] >= 0);
      const unsigned long long m = __ballot(valid);
      if (lane == 0) wsum[w] = (int)__popcll(m);
      __syncthreads();
      int wb = base;
#pragma unroll
      for (int k = 0; k < 4; ++k)
        if (k < w) wb += wsum[k];
      if (valid) {
        int off = (int)__popcll(m & ((1ull << lane) - 1));
        idxloc[c * CHUNK + wb + off] = i;
      } else if (i < natoms) {
        out[i] = 0.0f;  // masked atoms must be exactly 0
      }
      base += wsum[0] + wsum[1] + wsum[2] + wsum[3];
      __syncthreads();  // wsum reused next round
    }
    if (threadIdx.x == 0) cnt[c] = base;
    return;
  }
  // ---- weight retile (unchanged math) ----
  int idx = blockIdx.x * blockDim.x + threadIdx.x;
  if (idx < 512 * 256) {  // W1: K=256, N=512, KS=16
    int k = idx >> 9, n = idx & 511;
    int off = (((n >> 5) * 16 + (k >> 4)) << 9) + (n & 31) * 8 + (((k >> 3) & 1) << 8) + (k & 7);
    wt1[off] = (_Float16)W1[idx];
    return;
  }
  int i2 = idx - 512 * 256;
  if (i2 < 512 * 512) {  // W2: K=512, N=512, KS=32
    int k = i2 >> 9, n = i2 & 511;
    int off = (((n >> 5) * 32 + (k >> 4)) << 9) + (n & 31) * 8 + (((k >> 3) & 1) << 8) + (k & 7);
    wt2[off] = (_Float16)W2[i2];
    return;
  }
  int i3 = i2 - 512 * 512;
  if (i3 < 512 * 256) {  // W3: K=512, N=256, KS=32
    int k = i3 >> 8, n = i3 & 255;
    int off = (((n >> 5) * 32 + (k >> 4)) << 9) + (n & 31) * 8 + (((k >> 3) & 1) << 8) + (k & 7);
    wt3[off] = (_Float16)W3[i3];
    return;
  }
  int i4 = i3 - 512 * 256;
  if (i4 < 256) w4h[i4] = (_Float16)W4[i4];
}

// silu with raw v_rcp_f32 (no IEEE div sequence); ~1ulp, well within tolerance
__device__ __forceinline__ float fast_silu(float s) {
  float e = __expf(-s);
  float d = 1.0f + e;
  float r;
  asm("v_rcp_f32 %0, %1" : "=v"(r) : "v"(d));
  return s * r;
}

// ---------------- fused MLP ----------------
// R8 geometry (verified local optimum): 64 atoms/block, 512 threads = 8
// waves, FT=2, AT=2, acc 64 AGPR + 64 arch VGPR = exactly the 128-reg
// budget at 4 waves/EU; 2 blocks/CU -> 16 waves/CU in TWO independent
// barrier domains (R13: merging them costs 16%).
// Evidence: R9 FAILED (L3 prefetch thrash). R10 NEUTRAL (bias-fold+pre-
// barrier silu; kept). R11 falsified skew. R12 falsified 8 waves/CU. R13
// falsified single-domain pairing. R14 FAILED (in_sizes is elements).
// R15: compaction real, dispatches cost ~25us each. R16 WIN (360us):
// dispatch-free compaction. R17 WIN (352.6us): CHUNK=1024 scan + L4 fused
// into L3's register epilogue (conflicts 7.05M->5.93M).
// R18 (this round): cycle accounting says matrix-pipe floor is ~36% and
// the rest is A-load (weight) latency stall: the ~2.2MB/tile-gen X stream
// evicts the 1.03MB weight set from each XCD's 4MB L2, pushing A-loads to
// L3/HBM latency that the 2-deep prefetch can't cover. Fix: X staging
// loads (touched exactly once) become NON-TEMPORAL (evict-first), keeping
// weights L2-resident; out stores nt too.

#define MFMA(a, b, c) __builtin_amdgcn_mfma_f32_32x32x16_f16(a, b, c, 0, 0, 0)

template <int FT, int AT, int KS, int PIN, int POUT>
__device__ __forceinline__ void layer(const _Float16* __restrict__ wt,
                                      const float* __restrict__ bias,
                                      char* __restrict__ Hb,
                                      int wfeat, int lane) {
  const int lr = lane & 31;
  const int lh = lane >> 5;
  const int n0 = wfeat * (FT * 32);
  const int s0 = (lr & 31) << 4;  // row swizzle; (a*32+lr)&31 == lr&31
  const char* Bp = Hb + lr * PIN;
  const char* wp = (const char*)wt + (size_t)(wfeat * FT * KS) * 1024 + lh * 512 + lr * 16;

  // init acc = bias (folds epilogue bias-add into MFMA C-in; bv transient)
  f32x16 acc[FT][AT];
#pragma unroll
  for (int f = 0; f < FT; ++f)
#pragma unroll
    for (int rg = 0; rg < 4; ++rg) {
      const int feat = n0 + f * 32 + rg * 8 + lh * 4;
      const f32x4 bv = *(const f32x4*)(bias + feat);
#pragma unroll
      for (int a = 0; a < AT; ++a)
#pragma unroll
        for (int r = 0; r < 4; ++r) acc[f][a][rg * 4 + r] = bv[r];
    }

  half8 Af[FT], Ag[FT], Bf[AT], Bg[AT];
#pragma unroll
  for (int f = 0; f < FT; ++f) Af[f] = *(const half8*)(wp + f * (KS * 1024));
#pragma unroll
  for (int a = 0; a < AT; ++a)
    Bf[a] = *(const half8*)(Bp + a * 32 * PIN + ((lh * 16) ^ s0));

#pragma unroll 1
  for (int ks = 0; ks < KS - 2; ks += 2) {
#pragma unroll
    for (int f = 0; f < FT; ++f)
      Ag[f] = *(const half8*)(wp + f * (KS * 1024) + (ks + 1) * 1024);
#pragma unroll
    for (int a = 0; a < AT; ++a)
      Bg[a] = *(const half8*)(Bp + a * 32 * PIN + (((ks + 1) * 32 + lh * 16) ^ s0));
#pragma unroll
    for (int f = 0; f < FT; ++f)
#pragma unroll
      for (int a = 0; a < AT; ++a) acc[f][a] = MFMA(Af[f], Bf[a], acc[f][a]);
#pragma unroll
    for (int f = 0; f < FT; ++f)
      Af[f] = *(const half8*)(wp + f * (KS * 1024) + (ks + 2) * 1024);
#pragma unroll
    for (int a = 0; a < AT; ++a)
      Bf[a] = *(const half8*)(Bp + a * 32 * PIN + (((ks + 2) * 32 + lh * 16) ^ s0));
#pragma unroll
    for (int f = 0; f < FT; ++f)
#pragma unroll
      for (int a = 0; a < AT; ++a) acc[f][a] = MFMA(Ag[f], Bg[a], acc[f][a]);
  }
#pragma unroll
  for (int f = 0; f < FT; ++f)
    Ag[f] = *(const half8*)(wp + f * (KS * 1024) + (KS - 1) * 1024);
#pragma unroll
  for (int a = 0; a < AT; ++a)
    Bg[a] = *(const half8*)(Bp + a * 32 * PIN + ((((KS - 1) * 32) + lh * 16) ^ s0));
#pragma unroll
  for (int f = 0; f < FT; ++f)
#pragma unroll
    for (int a = 0; a < AT; ++a) acc[f][a] = MFMA(Af[f], Bf[a], acc[f][a]);
#pragma unroll
  for (int f = 0; f < FT; ++f)
#pragma unroll
    for (int a = 0; a < AT; ++a) acc[f][a] = MFMA(Ag[f], Bg[a], acc[f][a]);

  // silu in-place BEFORE the barrier (R10).
#pragma unroll
  for (int f = 0; f < FT; ++f)
#pragma unroll
    for (int a = 0; a < AT; ++a)
#pragma unroll
      for (int j = 0; j < 16; ++j) acc[f][a][j] = fast_silu(acc[f][a][j]);

  __syncthreads();  // all waves done reading input region; safe to overwrite

  // post-barrier: cvt -> fp16, write swizzled (2-way, free)
#pragma unroll
  for (int f = 0; f < FT; ++f) {
#pragma unroll
    for (int rg = 0; rg < 4; ++rg) {
      const int feat = n0 + f * 32 + rg * 8 + lh * 4;
#pragma unroll
      for (int a = 0; a < AT; ++a) {
        half4 h;
#pragma unroll
        for (int r = 0; r < 4; ++r) h[r] = (_Float16)acc[f][a][rg * 4 + r];
        const int row = a * 32 + lr;
        *(half4*)(Hb + row * POUT + ((feat * 2) ^ ((row & 31) << 4))) = h;
      }
    }
  }
}

extern "C" __global__ void __launch_bounds__(512, 4)
mlp_kernel(const float* __restrict__ X, const int* __restrict__ species,
           const _Float16* __restrict__ wt1, const float* __restrict__ b1,
           const _Float16* __restrict__ wt2, const float* __restrict__ b2,
           const _Float16* __restrict__ wt3, const float* __restrict__ b3,
           const _Float16* __restrict__ w4h, const float* __restrict__ b4,
           float* __restrict__ out, int natoms,
           const int* __restrict__ idxloc, const int* __restrict__ cnt, int nchunks) {
  __shared__ __align__(16) char H[64 * 1024];
  __shared__ int prefixS[NCHUNK_MAX + 1];  // exclusive chunk starts
  __shared__ int gidx[64];                 // source atom per staged row
  __shared__ int wtot[8];
  const int tid = threadIdx.x;
  const int lane = tid & 63;
  const int wid = tid >> 6;  // 8 feature-slice waves
  const long abase = (long)blockIdx.x * 64;

  int nvalid = natoms;
  if (idxloc) {
    // ---- per-block prefix scan of cnt[] (nchunks <= 512, 1 per thread) ----
    int v = (tid < nchunks) ? cnt[tid] : 0;
    int ws_ = v;
#pragma unroll
    for (int d = 1; d < 64; d <<= 1) {
      int o = __shfl_up(ws_, d);
      if (lane >= d) ws_ += o;
    }
    if (lane == 63) wtot[wid] = ws_;
    __syncthreads();
    int wbase = 0, tot = 0;
#pragma unroll
    for (int k = 0; k < 8; ++k) {
      if (k < wid) wbase += wtot[k];
      tot += wtot[k];
    }
    if (tid < nchunks) prefixS[tid] = wbase + ws_ - v;  // exclusive
    nvalid = tot;
    __syncthreads();  // prefixS ready
    if (abase >= nvalid) return;  // uniform whole-block exit
  }

  // ---- stage X[64x256] -> fp16 LDS, pitch 512B, swizzled ----
  // X rows are touched exactly once per dispatch -> NON-TEMPORAL loads
  // (evict-first) so the X stream does not evict the L2-resident weights
  // that the K-loop's 2-deep prefetch depends on (R18 mechanism).
  {
    const int r = tid >> 3, cg = tid & 7;
    long li = abase + r;
    const long lmax = (long)nvalid - 1;
    if (li > lmax) li = lmax;  // clamp: pad rows read a valid row, never stored
    long g = li;
    if (idxloc) {
      int lo = 0, hi = nchunks - 1;  // largest c with prefixS[c] <= li
      while (lo < hi) {
        int mid = (lo + hi + 1) >> 1;
        if (prefixS[mid] <= (int)li) lo = mid; else hi = mid - 1;
      }
      g = idxloc[lo * CHUNK + ((int)li - prefixS[lo])];
      if (cg == 0) gidx[r] = (int)g;
    }
    const float* xp = X + g * 256;
    const int sw = (r & 31) << 4;
#pragma unroll
    for (int j = 0; j < 8; ++j) {
      const int colh = cg * 4 + j * 32;
      f32x4 v = __builtin_nontemporal_load((const f32x4*)(xp + colh));
      half4 h;
#pragma unroll
      for (int e = 0; e < 4; ++e) h[e] = (_Float16)v[e];
      *(half4*)(H + r * 512 + ((colh * 2) ^ sw)) = h;
    }
  }
  __syncthreads();

  // L1: Xh[64x256] -> H1[64x512]   (8 wfeat x FT=2 -> 512 feats)
  layer<2, 2, 16, 512, 1024>(wt1, b1, H, wid, lane);
  __syncthreads();
  // L2: H1 -> H2[64x512]
  layer<2, 2, 32, 1024, 1024>(wt2, b2, H, wid, lane);
  __syncthreads();

  // ---- L3 (FT=1, AT=2, KS=32) with L4 fused into the register epilogue ----
  {
    const int lr = lane & 31;
    const int lh = lane >> 5;
    const int n0 = wid * 32;
    const int s0 = (lr & 31) << 4;
    const char* Bp = H + lr * 1024;
    const char* wp = (const char*)wt3 + (size_t)(wid * 32) * 1024 + lh * 512 + lr * 16;

    f32x16 acc[2];
#pragma unroll
    for (int rg = 0; rg < 4; ++rg) {
      const int feat = n0 + rg * 8 + lh * 4;
      const f32x4 bv = *(const f32x4*)(b3 + feat);
#pragma unroll
      for (int a = 0; a < 2; ++a)
#pragma unroll
        for (int r = 0; r < 4; ++r) acc[a][rg * 4 + r] = bv[r];
    }

    half8 Af, Ag, Bf[2], Bg[2];
    Af = *(const half8*)(wp);
#pragma unroll
    for (int a = 0; a < 2; ++a)
      Bf[a] = *(const half8*)(Bp + a * 32 * 1024 + ((lh * 16) ^ s0));

#pragma unroll 1
    for (int ks = 0; ks < 30; ks += 2) {
      Ag = *(const half8*)(wp + (ks + 1) * 1024);
#pragma unroll
      for (int a = 0; a < 2; ++a)
        Bg[a] = *(const half8*)(Bp + a * 32 * 1024 + (((ks + 1) * 32 + lh * 16) ^ s0));
#pragma unroll
      for (int a = 0; a < 2; ++a) acc[a] = MFMA(Af, Bf[a], acc[a]);
      Af = *(const half8*)(wp + (ks + 2) * 1024);
#pragma unroll
      for (int a = 0; a < 2; ++a)
        Bf[a] = *(const half8*)(Bp + a * 32 * 1024 + (((ks + 2) * 32 + lh * 16) ^ s0));
#pragma unroll
      for (int a = 0; a < 2; ++a) acc[a] = MFMA(Ag, Bg[a], acc[a]);
    }
    Ag = *(const half8*)(wp + 31 * 1024);
#pragma unroll
    for (int a = 0; a < 2; ++a)
      Bg[a] = *(const half8*)(Bp + a * 32 * 1024 + ((31 * 32 + lh * 16) ^ s0));
#pragma unroll
    for (int a = 0; a < 2; ++a) acc[a] = MFMA(Af, Bf[a], acc[a]);
#pragma unroll
    for (int a = 0; a < 2; ++a) acc[a] = MFMA(Ag, Bg[a], acc[a]);

    // silu + in-register dot with w4 slice (feats n0+rg*8+lh*4+r)
    float s[2] = {0.0f, 0.0f};
#pragma unroll
    for (int rg = 0; rg < 4; ++rg) {
      half4 wv = *(const half4*)(w4h + n0 + rg * 8 + lh * 4);
#pragma unroll
      for (int r = 0; r < 4; ++r) {
        const float wf = (float)wv[r];
#pragma unroll
        for (int a = 0; a < 2; ++a)
          s[a] += fast_silu(acc[a][rg * 4 + r]) * wf;
      }
    }
    // combine the two feat-halves (lh=0/1) held by lanes lr and lr+32
    s[0] += __shfl_xor(s[0], 32);
    s[1] += __shfl_xor(s[1], 32);

    __syncthreads();  // all waves done reading H2 -> safe to overwrite with P
    float* P = (float*)H;  // P[atom][8] partials, 2KB
    if (lh == 0) {
      P[(0 * 32 + lr) * 8 + wid] = s[0];
      P[(1 * 32 + lr) * 8 + wid] = s[1];
    }
  }
  __syncthreads();

  // final reduce: out[atom] = sum_w P[atom][w] + b4
  {
    const float* P = (const float*)H;
    const int atom = tid >> 3, part = tid & 7;
    float sum = P[atom * 8 + part];
    sum += __shfl_xor(sum, 1);
    sum += __shfl_xor(sum, 2);
    sum += __shfl_xor(sum, 4);
    if (part == 0) {
      const long li = abase + atom;
      if (li < nvalid) {
        float r = sum + b4[0];
        if (idxloc) {
          __builtin_nontemporal_store(r, &out[gidx[atom]]);  // masked zeroed in prep
        } else {
          float v = (species[li] >= 0) ? r : 0.0f;
          __builtin_nontemporal_store(v, &out[li]);
        }
      }
    }
  }
}

extern "C" void kernel_launch(void* const* d_in, const int* in_sizes, int n_in,
                              void* d_out, int out_size, void* d_ws, size_t ws_size,
                              hipStream_t stream) {
  const float* X = (const float*)d_in[0];
  const int* species = (const int*)d_in[1];
  const float* W1 = (const float*)d_in[2];
  const float* b1 = (const float*)d_in[3];
  const float* W2 = (const float*)d_in[4];
  const float* b2 = (const float*)d_in[5];
  const float* W3 = (const float*)d_in[6];
  const float* b3 = (const float*)d_in[7];
  const float* W4 = (const float*)d_in[8];
  const float* b4 = (const float*)d_in[9];
  float* out = (float*)d_out;
  const int natoms = in_sizes[0] / 256;  // in_sizes is ELEMENTS (R14 lesson)

  char* ws = (char*)d_ws;
  _Float16* wt1 = (_Float16*)(ws);                             // 512*256*2 B
  _Float16* wt2 = (_Float16*)(ws + 262144);                    // 512*512*2 B
  _Float16* wt3 = (_Float16*)(ws + 262144 + 524288);           // 256*512*2 B
  _Float16* w4h = (_Float16*)(ws + 262144 + 524288 + 262144);  // 512 B
  int* cnt = (int*)(ws + 1049088);                             // nchunks*4 B
  int* idxloc = (int*)(ws + 1049088 + 4096);                   // natoms*4 B (padded region)

  const int nchunks = (natoms + CHUNK - 1) / CHUNK;
  const size_t ws_needed = 1049088 + 4096 + (size_t)nchunks * CHUNK * 4;
  const bool use_compact = (ws_size >= ws_needed) && (nchunks <= NCHUNK_MAX);

  const int prep_total = 512 * 256 + 512 * 512 + 256 * 512 + 256;
  const int nprep = (prep_total + 255) / 256;
  const int nblk = nprep + (use_compact ? nchunks : 0);
  hipLaunchKernelGGL(prep_compact, dim3(nblk), dim3(256), 0, stream,
                     W1, W2, W3, W4, wt1, wt2, wt3, w4h,
                     species, idxloc, cnt, out, natoms, nprep);

  const int nblocks = (natoms + 63) / 64;  // worst case; surplus blocks exit early
  hipLaunchKernelGGL(mlp_kernel, dim3(nblocks), dim3(512), 0, stream,
                     X, species, wt1, b1, wt2, b2, wt3, b3, w4h, b4, out, natoms,
                     use_compact ? idxloc : (const int*)nullptr,
                     use_compact ? (const int*)cnt : (const int*)nullptr, nchunks);
}

// Round 11
// 343.854 us; speedup vs baseline: 1.3353x; 1.0187x over previous
//
#include <hip/hip_runtime.h>

typedef _Float16 half8 __attribute__((ext_vector_type(8)));
typedef _Float16 half4 __attribute__((ext_vector_type(4)));
typedef float f32x4 __attribute__((ext_vector_type(4)));
typedef float f32x16 __attribute__((ext_vector_type(16)));

#define CHUNK 1024
#define NCHUNK_MAX 512  // supports up to 524288 atoms in compact mode

// ---------------- prologue: weights retile + chunk-local compaction --------
// One dispatch, two block roles:
//   blocks [0, nprep): cast + retile weights to fp16 MFMA tiles.
//   blocks [nprep, nprep+nchunks): chunk c (1024 atoms) self-compacts into
//     idxloc[c*1024 ...] and writes cnt[c]. No atomics -> no memset, no
//     extra dispatch (R15: each dispatch costs ~25us on this bench).
__global__ void prep_compact(const float* __restrict__ W1, const float* __restrict__ W2,
                             const float* __restrict__ W3, const float* __restrict__ W4,
                             _Float16* __restrict__ wt1, _Float16* __restrict__ wt2,
                             _Float16* __restrict__ wt3, _Float16* __restrict__ w4h,
                             const int* __restrict__ species, int* __restrict__ idxloc,
                             int* __restrict__ cnt, float* __restrict__ out,
                             int natoms, int nprep) {
  __shared__ int wsum[4];
  if (blockIdx.x >= nprep) {
    // ---- chunk-local compaction: 1024 atoms, 256 threads, 4 sub-rounds ----
    const int c = blockIdx.x - nprep;
    const int lane = threadIdx.x & 63, w = threadIdx.x >> 6;
    int base = 0;
#pragma unroll 1
    for (int j = 0; j < 4; ++j) {
      const int i = c * CHUNK + j * 256 + threadIdx.x;
      const bool valid = (i < natoms) && (species[i] >= 0);
      const unsigned long long m = __ballot(valid);
      if (lane == 0) wsum[w] = (int)__popcll(m);
      __syncthreads();
      int wb = base;
#pragma unroll
      for (int k = 0; k < 4; ++k)
        if (k < w) wb += wsum[k];
      if (valid) {
        int off = (int)__popcll(m & ((1ull << lane) - 1));
        idxloc[c * CHUNK + wb + off] = i;
      } else if (i < natoms) {
        out[i] = 0.0f;  // masked atoms must be exactly 0
      }
      base += wsum[0] + wsum[1] + wsum[2] + wsum[3];
      __syncthreads();  // wsum reused next round
    }
    if (threadIdx.x == 0) cnt[c] = base;
    return;
  }
  // ---- weight retile (unchanged math) ----
  int idx = blockIdx.x * blockDim.x + threadIdx.x;
  if (idx < 512 * 256) {  // W1: K=256, N=512, KS=16
    int k = idx >> 9, n = idx & 511;
    int off = (((n >> 5) * 16 + (k >> 4)) << 9) + (n & 31) * 8 + (((k >> 3) & 1) << 8) + (k & 7);
    wt1[off] = (_Float16)W1[idx];
    return;
  }
  int i2 = idx - 512 * 256;
  if (i2 < 512 * 512) {  // W2: K=512, N=512, KS=32
    int k = i2 >> 9, n = i2 & 511;
    int off = (((n >> 5) * 32 + (k >> 4)) << 9) + (n & 31) * 8 + (((k >> 3) & 1) << 8) + (k & 7);
    wt2[off] = (_Float16)W2[i2];
    return;
  }
  int i3 = i2 - 512 * 512;
  if (i3 < 512 * 256) {  // W3: K=512, N=256, KS=32
    int k = i3 >> 8, n = i3 & 255;
    int off = (((n >> 5) * 32 + (k >> 4)) << 9) + (n & 31) * 8 + (((k >> 3) & 1) << 8) + (k & 7);
    wt3[off] = (_Float16)W3[i3];
    return;
  }
  int i4 = i3 - 512 * 256;
  if (i4 < 256) w4h[i4] = (_Float16)W4[i4];
}

// silu with raw v_rcp_f32 (no IEEE div sequence); ~1ulp, well within tolerance
__device__ __forceinline__ float fast_silu(float s) {
  float e = __expf(-s);
  float d = 1.0f + e;
  float r;
  asm("v_rcp_f32 %0, %1" : "=v"(r) : "v"(d));
  return s * r;
}

// ---------------- fused MLP ----------------
// R8 geometry (verified local optimum): 64 atoms/block, 512 threads = 8
// waves, FT=2, AT=2, acc 64 AGPR + 64 arch VGPR = exactly the 128-reg
// budget at 4 waves/EU; 2 blocks/CU -> 16 waves/CU in TWO independent
// barrier domains (R13: merging them costs 16%).
// Evidence: R9 FAILED (L3 prefetch thrash). R10 NEUTRAL (kept). R11
// falsified skew. R12 falsified 8 waves/CU. R13 falsified single-domain.
// R14 FAILED (in_sizes is elements). R15: dispatches cost ~25us each.
// R16 WIN (360): dispatch-free compaction. R17 WIN (352.6): CHUNK=1024 +
// L4 fused into L3 epilogue. R18 small WIN (350.3): NT X-loads
// (MfmaUtil 37->40, FETCH -3MB).
// R19 (this round): recalibrated accounting (true MFMA-pipe busy ~9%,
// trans ~11%, VALU ~10%, ~70% latency stall; register-cornered against
// deeper prefetch). Remaining zero-register lever: layer-entry A-load
// latency (~300-900cy x3 boundaries + L1 entry) is exposed after each
// barrier because the compiler won't hoist global loads across
// __syncthreads. Fix: cross-layer A-pipeline — each layer pre-loads the
// NEXT layer's first A-fragments BEFORE its epilogue (weights independent
// of H; silu+cvt+write ~2.5k cyc of cover); L1's first A issues at kernel
// entry under the scan+staging phase.

#define MFMA(a, b, c) __builtin_amdgcn_mfma_f32_32x32x16_f16(a, b, c, 0, 0, 0)

// A0: preloaded first A-fragments (ks=0) for THIS layer.
// If NFT>0: before the epilogue, load next layer's first A-fragments
// (wfeat stride NKS) into Anext.
template <int FT, int AT, int KS, int PIN, int POUT, int NFT, int NKS>
__device__ __forceinline__ void layer(const _Float16* __restrict__ wt,
                                      const float* __restrict__ bias,
                                      char* __restrict__ Hb,
                                      int wfeat, int lane,
                                      const half8* __restrict__ A0,
                                      const _Float16* __restrict__ next_wt,
                                      half8* __restrict__ Anext) {
  const int lr = lane & 31;
  const int lh = lane >> 5;
  const int n0 = wfeat * (FT * 32);
  const int s0 = (lr & 31) << 4;  // row swizzle; (a*32+lr)&31 == lr&31
  const char* Bp = Hb + lr * PIN;
  const char* wp = (const char*)wt + (size_t)(wfeat * FT * KS) * 1024 + lh * 512 + lr * 16;

  // init acc = bias (folds epilogue bias-add into MFMA C-in; bv transient)
  f32x16 acc[FT][AT];
#pragma unroll
  for (int f = 0; f < FT; ++f)
#pragma unroll
    for (int rg = 0; rg < 4; ++rg) {
      const int feat = n0 + f * 32 + rg * 8 + lh * 4;
      const f32x4 bv = *(const f32x4*)(bias + feat);
#pragma unroll
      for (int a = 0; a < AT; ++a)
#pragma unroll
        for (int r = 0; r < 4; ++r) acc[f][a][rg * 4 + r] = bv[r];
    }

  half8 Af[FT], Ag[FT], Bf[AT], Bg[AT];
#pragma unroll
  for (int f = 0; f < FT; ++f) Af[f] = A0[f];  // preloaded (R19)
#pragma unroll
  for (int a = 0; a < AT; ++a)
    Bf[a] = *(const half8*)(Bp + a * 32 * PIN + ((lh * 16) ^ s0));

#pragma unroll 1
  for (int ks = 0; ks < KS - 2; ks += 2) {
#pragma unroll
    for (int f = 0; f < FT; ++f)
      Ag[f] = *(const half8*)(wp + f * (KS * 1024) + (ks + 1) * 1024);
#pragma unroll
    for (int a = 0; a < AT; ++a)
      Bg[a] = *(const half8*)(Bp + a * 32 * PIN + (((ks + 1) * 32 + lh * 16) ^ s0));
#pragma unroll
    for (int f = 0; f < FT; ++f)
#pragma unroll
      for (int a = 0; a < AT; ++a) acc[f][a] = MFMA(Af[f], Bf[a], acc[f][a]);
#pragma unroll
    for (int f = 0; f < FT; ++f)
      Af[f] = *(const half8*)(wp + f * (KS * 1024) + (ks + 2) * 1024);
#pragma unroll
    for (int a = 0; a < AT; ++a)
      Bf[a] = *(const half8*)(Bp + a * 32 * PIN + (((ks + 2) * 32 + lh * 16) ^ s0));
#pragma unroll
    for (int f = 0; f < FT; ++f)
#pragma unroll
      for (int a = 0; a < AT; ++a) acc[f][a] = MFMA(Ag[f], Bg[a], acc[f][a]);
  }
#pragma unroll
  for (int f = 0; f < FT; ++f)
    Ag[f] = *(const half8*)(wp + f * (KS * 1024) + (KS - 1) * 1024);
#pragma unroll
  for (int a = 0; a < AT; ++a)
    Bg[a] = *(const half8*)(Bp + a * 32 * PIN + ((((KS - 1) * 32) + lh * 16) ^ s0));
#pragma unroll
  for (int f = 0; f < FT; ++f)
#pragma unroll
    for (int a = 0; a < AT; ++a) acc[f][a] = MFMA(Af[f], Bf[a], acc[f][a]);
#pragma unroll
  for (int f = 0; f < FT; ++f)
#pragma unroll
    for (int a = 0; a < AT; ++a) acc[f][a] = MFMA(Ag[f], Bg[a], acc[f][a]);

  // R19: issue next layer's first A-loads NOW — latency hides under the
  // silu + barrier + epilogue-write phase (~2.5k cyc). Buffer regs Af/Ag
  // are dead after the tail; Anext reuses that budget.
  if constexpr (NFT > 0) {
    const char* wpn = (const char*)next_wt + (size_t)(wfeat * NFT * NKS) * 1024 + lh * 512 + lr * 16;
#pragma unroll
    for (int f = 0; f < NFT; ++f)
      Anext[f] = *(const half8*)(wpn + f * (NKS * 1024));
  }

  // silu in-place BEFORE the barrier (R10).
#pragma unroll
  for (int f = 0; f < FT; ++f)
#pragma unroll
    for (int a = 0; a < AT; ++a)
#pragma unroll
      for (int j = 0; j < 16; ++j) acc[f][a][j] = fast_silu(acc[f][a][j]);

  __syncthreads();  // all waves done reading input region; safe to overwrite

  // post-barrier: cvt -> fp16, write swizzled (2-way, free)
#pragma unroll
  for (int f = 0; f < FT; ++f) {
#pragma unroll
    for (int rg = 0; rg < 4; ++rg) {
      const int feat = n0 + f * 32 + rg * 8 + lh * 4;
#pragma unroll
      for (int a = 0; a < AT; ++a) {
        half4 h;
#pragma unroll
        for (int r = 0; r < 4; ++r) h[r] = (_Float16)acc[f][a][rg * 4 + r];
        const int row = a * 32 + lr;
        *(half4*)(Hb + row * POUT + ((feat * 2) ^ ((row & 31) << 4))) = h;
      }
    }
  }
}

extern "C" __global__ void __launch_bounds__(512, 4)
mlp_kernel(const float* __restrict__ X, const int* __restrict__ species,
           const _Float16* __restrict__ wt1, const float* __restrict__ b1,
           const _Float16* __restrict__ wt2, const float* __restrict__ b2,
           const _Float16* __restrict__ wt3, const float* __restrict__ b3,
           const _Float16* __restrict__ w4h, const float* __restrict__ b4,
           float* __restrict__ out, int natoms,
           const int* __restrict__ idxloc, const int* __restrict__ cnt, int nchunks) {
  __shared__ __align__(16) char H[64 * 1024];
  __shared__ int prefixS[NCHUNK_MAX + 1];  // exclusive chunk starts
  __shared__ int gidx[64];                 // source atom per staged row
  __shared__ int wtot[8];
  const int tid = threadIdx.x;
  const int lane = tid & 63;
  const int wid = tid >> 6;  // 8 feature-slice waves
  const long abase = (long)blockIdx.x * 64;

  // R19: L1 first-A preload at kernel entry — latency hides under the
  // scan + staging phase (~3k cyc). Harmless for early-exit blocks.
  half8 A1[2], A2[2], A3[1];
  {
    const char* wp1 = (const char*)wt1 + (size_t)(wid * 2 * 16) * 1024 +
                      (lane >> 5) * 512 + (lane & 31) * 16;
    A1[0] = *(const half8*)(wp1);
    A1[1] = *(const half8*)(wp1 + 16 * 1024);
  }

  int nvalid = natoms;
  if (idxloc) {
    // ---- per-block prefix scan of cnt[] (nchunks <= 512, 1 per thread) ----
    int v = (tid < nchunks) ? cnt[tid] : 0;
    int ws_ = v;
#pragma unroll
    for (int d = 1; d < 64; d <<= 1) {
      int o = __shfl_up(ws_, d);
      if (lane >= d) ws_ += o;
    }
    if (lane == 63) wtot[wid] = ws_;
    __syncthreads();
    int wbase = 0, tot = 0;
#pragma unroll
    for (int k = 0; k < 8; ++k) {
      if (k < wid) wbase += wtot[k];
      tot += wtot[k];
    }
    if (tid < nchunks) prefixS[tid] = wbase + ws_ - v;  // exclusive
    nvalid = tot;
    __syncthreads();  // prefixS ready
    if (abase >= nvalid) return;  // uniform whole-block exit
  }

  // ---- stage X[64x256] -> fp16 LDS, pitch 512B, swizzled ----
  // NT loads: X rows touched exactly once -> evict-first keeps weights
  // L2-resident (R18).
  {
    const int r = tid >> 3, cg = tid & 7;
    long li = abase + r;
    const long lmax = (long)nvalid - 1;
    if (li > lmax) li = lmax;  // clamp: pad rows read a valid row, never stored
    long g = li;
    if (idxloc) {
      int lo = 0, hi = nchunks - 1;  // largest c with prefixS[c] <= li
      while (lo < hi) {
        int mid = (lo + hi + 1) >> 1;
        if (prefixS[mid] <= (int)li) lo = mid; else hi = mid - 1;
      }
      g = idxloc[lo * CHUNK + ((int)li - prefixS[lo])];
      if (cg == 0) gidx[r] = (int)g;
    }
    const float* xp = X + g * 256;
    const int sw = (r & 31) << 4;
#pragma unroll
    for (int j = 0; j < 8; ++j) {
      const int colh = cg * 4 + j * 32;
      f32x4 v = __builtin_nontemporal_load((const f32x4*)(xp + colh));
      half4 h;
#pragma unroll
      for (int e = 0; e < 4; ++e) h[e] = (_Float16)v[e];
      *(half4*)(H + r * 512 + ((colh * 2) ^ sw)) = h;
    }
  }
  __syncthreads();

  // L1: Xh[64x256] -> H1[64x512]; prefetches L2's first A into A2
  layer<2, 2, 16, 512, 1024, 2, 32>(wt1, b1, H, wid, lane, A1, wt2, A2);
  __syncthreads();
  // L2: H1 -> H2[64x512]; prefetches L3's first A into A3
  layer<2, 2, 32, 1024, 1024, 1, 32>(wt2, b2, H, wid, lane, A2, wt3, A3);
  __syncthreads();

  // ---- L3 (FT=1, AT=2, KS=32) with L4 fused into the register epilogue ----
  {
    const int lr = lane & 31;
    const int lh = lane >> 5;
    const int n0 = wid * 32;
    const int s0 = (lr & 31) << 4;
    const char* Bp = H + lr * 1024;
    const char* wp = (const char*)wt3 + (size_t)(wid * 32) * 1024 + lh * 512 + lr * 16;

    f32x16 acc[2];
#pragma unroll
    for (int rg = 0; rg < 4; ++rg) {
      const int feat = n0 + rg * 8 + lh * 4;
      const f32x4 bv = *(const f32x4*)(b3 + feat);
#pragma unroll
      for (int a = 0; a < 2; ++a)
#pragma unroll
        for (int r = 0; r < 4; ++r) acc[a][rg * 4 + r] = bv[r];
    }

    half8 Af, Ag, Bf[2], Bg[2];
    Af = A3[0];  // preloaded by L2 (R19)
#pragma unroll
    for (int a = 0; a < 2; ++a)
      Bf[a] = *(const half8*)(Bp + a * 32 * 1024 + ((lh * 16) ^ s0));

#pragma unroll 1
    for (int ks = 0; ks < 30; ks += 2) {
      Ag = *(const half8*)(wp + (ks + 1) * 1024);
#pragma unroll
      for (int a = 0; a < 2; ++a)
        Bg[a] = *(const half8*)(Bp + a * 32 * 1024 + (((ks + 1) * 32 + lh * 16) ^ s0));
#pragma unroll
      for (int a = 0; a < 2; ++a) acc[a] = MFMA(Af, Bf[a], acc[a]);
      Af = *(const half8*)(wp + (ks + 2) * 1024);
#pragma unroll
      for (int a = 0; a < 2; ++a)
        Bf[a] = *(const half8*)(Bp + a * 32 * 1024 + (((ks + 2) * 32 + lh * 16) ^ s0));
#pragma unroll
      for (int a = 0; a < 2; ++a) acc[a] = MFMA(Ag, Bg[a], acc[a]);
    }
    Ag = *(const half8*)(wp + 31 * 1024);
#pragma unroll
    for (int a = 0; a < 2; ++a)
      Bg[a] = *(const half8*)(Bp + a * 32 * 1024 + ((31 * 32 + lh * 16) ^ s0));
#pragma unroll
    for (int a = 0; a < 2; ++a) acc[a] = MFMA(Af, Bf[a], acc[a]);
#pragma unroll
    for (int a = 0; a < 2; ++a) acc[a] = MFMA(Ag, Bg[a], acc[a]);

    // silu + in-register dot with w4 slice (feats n0+rg*8+lh*4+r)
    float s[2] = {0.0f, 0.0f};
#pragma unroll
    for (int rg = 0; rg < 4; ++rg) {
      half4 wv = *(const half4*)(w4h + n0 + rg * 8 + lh * 4);
#pragma unroll
      for (int r = 0; r < 4; ++r) {
        const float wf = (float)wv[r];
#pragma unroll
        for (int a = 0; a < 2; ++a)
          s[a] += fast_silu(acc[a][rg * 4 + r]) * wf;
      }
    }
    // combine the two feat-halves (lh=0/1) held by lanes lr and lr+32
    s[0] += __shfl_xor(s[0], 32);
    s[1] += __shfl_xor(s[1], 32);

    __syncthreads();  // all waves done reading H2 -> safe to overwrite with P
    float* P = (float*)H;  // P[atom][8] partials, 2KB
    if (lh == 0) {
      P[(0 * 32 + lr) * 8 + wid] = s[0];
      P[(1 * 32 + lr) * 8 + wid] = s[1];
    }
  }
  __syncthreads();

  // final reduce: out[atom] = sum_w P[atom][w] + b4
  {
    const float* P = (const float*)H;
    const int atom = tid >> 3, part = tid & 7;
    float sum = P[atom * 8 + part];
    sum += __shfl_xor(sum, 1);
    sum += __shfl_xor(sum, 2);
    sum += __shfl_xor(sum, 4);
    if (part == 0) {
      const long li = abase + atom;
      if (li < nvalid) {
        float r = sum + b4[0];
        if (idxloc) {
          __builtin_nontemporal_store(r, &out[gidx[atom]]);  // masked zeroed in prep
        } else {
          float v = (species[li] >= 0) ? r : 0.0f;
          __builtin_nontemporal_store(v, &out[li]);
        }
      }
    }
  }
}

extern "C" void kernel_launch(void* const* d_in, const int* in_sizes, int n_in,
                              void* d_out, int out_size, void* d_ws, size_t ws_size,
                              hipStream_t stream) {
  const float* X = (const float*)d_in[0];
  const int* species = (const int*)d_in[1];
  const float* W1 = (const float*)d_in[2];
  const float* b1 = (const float*)d_in[3];
  const float* W2 = (const float*)d_in[4];
  const float* b2 = (const float*)d_in[5];
  const float* W3 = (const float*)d_in[6];
  const float* b3 = (const float*)d_in[7];
  const float* W4 = (const float*)d_in[8];
  const float* b4 = (const float*)d_in[9];
  float* out = (float*)d_out;
  const int natoms = in_sizes[0] / 256;  // in_sizes is ELEMENTS (R14 lesson)

  char* ws = (char*)d_ws;
  _Float16* wt1 = (_Float16*)(ws);                             // 512*256*2 B
  _Float16* wt2 = (_Float16*)(ws + 262144);                    // 512*512*2 B
  _Float16* wt3 = (_Float16*)(ws + 262144 + 524288);           // 256*512*2 B
  _Float16* w4h = (_Float16*)(ws + 262144 + 524288 + 262144);  // 512 B
  int* cnt = (int*)(ws + 1049088);                             // nchunks*4 B
  int* idxloc = (int*)(ws + 1049088 + 4096);                   // natoms*4 B (padded region)

  const int nchunks = (natoms + CHUNK - 1) / CHUNK;
  const size_t ws_needed = 1049088 + 4096 + (size_t)nchunks * CHUNK * 4;
  const bool use_compact = (ws_size >= ws_needed) && (nchunks <= NCHUNK_MAX);

  const int prep_total = 512 * 256 + 512 * 512 + 256 * 512 + 256;
  const int nprep = (prep_total + 255) / 256;
  const int nblk = nprep + (use_compact ? nchunks : 0);
  hipLaunchKernelGGL(prep_compact, dim3(nblk), dim3(256), 0, stream,
                     W1, W2, W3, W4, wt1, wt2, wt3, w4h,
                     species, idxloc, cnt, out, natoms, nprep);

  const int nblocks = (natoms + 63) / 64;  // worst case; surplus blocks exit early
  hipLaunchKernelGGL(mlp_kernel, dim3(nblocks), dim3(512), 0, stream,
                     X, species, wt1, b1, wt2, b2, wt3, b3, w4h, b4, out, natoms,
                     use_compact ? idxloc : (const int*)nullptr,
                     use_compact ? (const int*)cnt : (const int*)nullptr, nchunks);
}